// Round 7
// baseline (29098.810 us; speedup 1.0000x reference)
//
#include <hip/hip_runtime.h>
#include <hip/hip_bf16.h>
#include <math.h>

typedef __attribute__((ext_vector_type(8))) short bfrag8;   // 8 x bf16
typedef __attribute__((ext_vector_type(4))) float f32x4;    // MFMA accumulator
#define AGENT __HIP_MEMORY_SCOPE_AGENT

static __device__ __forceinline__ float b2f(unsigned short u) {
  union { unsigned int i; float f; } v; v.i = ((unsigned int)u) << 16; return v.f;
}
static __device__ __forceinline__ unsigned short f2b(float f) {
  union { float f; unsigned int i; } v; v.f = f;
  unsigned int i = v.i;
  return (unsigned short)((i + 0x7FFFu + ((i >> 16) & 1u)) >> 16);
}
static __device__ __forceinline__ float sigf(float x) { return 1.f / (1.f + __expf(-x)); }

// ---------------- workspace layout (bytes) ----------------
// cnt   [0,1024)        barrier lines (16 x 64B) + cnt[255] = watchdog flag
// scan  [4096,102400)   cvec/coef/inv2 (3 x 8192 fp32)
// pe    [102400,153600) 100x128 fp32
// h1    [153600,284672) 2 slots x 32x1024 bf16
// h2    [284672,415744)
// cst   [415744,677888) c1,c2 save: 2 x 256x32x4 fp32
// LO:  inp1c @ 720896
// HI:  melpre @ 720896 (4,096,000) ; wbf @ 4,849,664 (10,485,760) ; inp1c @ 16,777,216

// ---------------- init ----------------
__global__ void k_init(unsigned int* hzero, unsigned int* cnt, float* pe) {
  int idx = blockIdx.x * 256 + threadIdx.x;
  if (idx < 256) cnt[idx] = 0u;
  if (idx < 65536) hzero[idx] = 0u;                     // h1+h2 both slots
  if (idx < 6400) {
    int p = idx >> 6, i = idx & 63;
    float freq = __expf(-(float)(2 * i) * 0.0719557842162201f); // ln(10000)/128
    float a = (float)p * freq;
    pe[p * 128 + 2 * i]     = sinf(a);
    pe[p * 128 + 2 * i + 1] = cosf(a);
  }
}

// ---------------- prenet -> inp1c[:, 0:256] ----------------
__global__ __launch_bounds__(256) void k_prenet(const float* __restrict__ din,
                                                const float* __restrict__ u1,
                                                const float* __restrict__ u2,
                                                const float* __restrict__ Wp1,
                                                const float* __restrict__ Wp2,
                                                unsigned short* inp1c, int t0, int tbeg) {
  __shared__ float dec[2560];
  __shared__ float X1[8192];
  int t = tbeg + blockIdx.x, tid = threadIdx.x;
  int tt = t - t0;
  for (int i = tid; i < 2560; i += 256) {
    int b = i / 80, f = i % 80;
    dec[i] = (t == 0) ? 0.f : din[((size_t)b * 80 + f) * 800 + (t - 1)];
  }
  __syncthreads();
  int n = tid;
  for (int b = 0; b < 32; ++b) {
    float s = 0.f;
    const float* w = Wp1 + n * 80;
    const float* d = dec + b * 80;
#pragma unroll 8
    for (int f = 0; f < 80; ++f) s += d[f] * w[f];
    s = fmaxf(s, 0.f);
    float m = (u1[((size_t)t * 32 + b) * 256 + n] >= 0.5f) ? 2.f : 0.f;
    X1[b * 256 + n] = s * m;
  }
  __syncthreads();
  for (int b = 0; b < 32; ++b) {
    float s = 0.f;
    const float* w = Wp2 + n * 256;
    const float* x = X1 + b * 256;
#pragma unroll 8
    for (int kk = 0; kk < 256; ++kk) s += x[kk] * w[kk];
    s = fmaxf(s, 0.f);
    float m = (u2[((size_t)t * 32 + b) * 256 + n] >= 0.5f) ? 2.f : 0.f;
    inp1c[((size_t)tt * 32 + b) * 1280 + n] = f2b(s * m);
  }
}

// ---------------- attention precompute ----------------
__global__ __launch_bounds__(256) void k_attn_prep(const float* __restrict__ dur,
                                                   const float* __restrict__ range,
                                                   float* cvec, float* coef, float* inv2) {
  __shared__ float s[256];
  int b = blockIdx.x, e = threadIdx.x;
  float d = dur[b * 256 + e];
  s[e] = d;
  __syncthreads();
  for (int off = 1; off < 256; off <<= 1) {
    float v = (e >= off) ? s[e - off] : 0.f;
    __syncthreads();
    s[e] = s[e] + v;
    __syncthreads();
  }
  float c = s[e] - 0.5f * d;
  float sg = range[b * 256 + e] + 1e-5f;
  cvec[b * 256 + e] = c;
  coef[b * 256 + e] = rsqrtf(6.283185307179586f * sg * sg);
  inv2[b * 256 + e] = 1.f / (2.f * sg * sg);
}

// ---------------- alignments output (fp32) ----------------
__global__ __launch_bounds__(256) void k_attn(const float* __restrict__ cvec,
                                              const float* __restrict__ coef,
                                              const float* __restrict__ inv2,
                                              float* out_align) {
  __shared__ float red[4];
  int t = blockIdx.x, b = blockIdx.y, e = threadIdx.x;
  float dt = (float)t - cvec[b * 256 + e];
  float p = coef[b * 256 + e] * __expf(-dt * dt * inv2[b * 256 + e]) + 1e-5f;
  float s = p;
#pragma unroll
  for (int o = 1; o < 64; o <<= 1) s += __shfl_xor(s, o);
  if ((e & 63) == 0) red[e >> 6] = s;
  __syncthreads();
  float tot = red[0] + red[1] + red[2] + red[3];
  out_align[((size_t)b * 800 + t) * 256 + e] = p / tot;
}

// ---------------- context -> inp1c[:,256:1152] ----------------
__global__ __launch_bounds__(256) void k_ctx(const float* __restrict__ cvec,
                                             const float* __restrict__ coef,
                                             const float* __restrict__ inv2,
                                             const float* __restrict__ mem,
                                             unsigned short* inp1c,
                                             int t0, int tbeg, int tend) {
  __shared__ float wl[4096];
  __shared__ float rinv[16];
  int b = blockIdx.y, tB = tbeg + blockIdx.x * 16, tid = threadIdx.x;
  int nt = tend - tB; if (nt > 16) nt = 16;
  float cv = cvec[b * 256 + tid], co = coef[b * 256 + tid], iv = inv2[b * 256 + tid];
  for (int s = 0; s < nt; ++s) {
    float d = (float)(tB + s) - cv;
    wl[s * 256 + tid] = co * __expf(-d * d * iv) + 1e-5f;
  }
  for (int s = nt; s < 16; ++s) wl[s * 256 + tid] = 0.f;
  __syncthreads();
  int wv = tid >> 6, ln = tid & 63;
  for (int s = wv; s < nt; s += 4) {
    float x = wl[s * 256 + ln] + wl[s * 256 + 64 + ln] + wl[s * 256 + 128 + ln] + wl[s * 256 + 192 + ln];
#pragma unroll
    for (int o = 1; o < 64; o <<= 1) x += __shfl_xor(x, o);
    if (ln == 0) rinv[s] = 1.f / x;
  }
  __syncthreads();
  for (int s = 0; s < nt; ++s) wl[s * 256 + tid] *= rinv[s];
  __syncthreads();
  float acc[16][4];
#pragma unroll
  for (int s = 0; s < 16; ++s) { acc[s][0] = 0.f; acc[s][1] = 0.f; acc[s][2] = 0.f; acc[s][3] = 0.f; }
  for (int e = 0; e < 256; ++e) {
    const float* mrow = mem + ((size_t)b * 256 + e) * 896;
    float m0 = mrow[tid], m1 = mrow[tid + 256], m2 = mrow[tid + 512];
    float m3 = (tid < 128) ? mrow[tid + 768] : 0.f;
#pragma unroll
    for (int s = 0; s < 16; ++s) {
      float w = wl[s * 256 + e];
      acc[s][0] += w * m0; acc[s][1] += w * m1; acc[s][2] += w * m2; acc[s][3] += w * m3;
    }
  }
  for (int s = 0; s < nt; ++s) {
    size_t base = ((size_t)(tB - t0 + s) * 32 + b) * 1280 + 256;
    inp1c[base + tid]       = f2b(acc[s][0]);
    inp1c[base + tid + 256] = f2b(acc[s][1]);
    inp1c[base + tid + 512] = f2b(acc[s][2]);
    if (tid < 128) inp1c[base + tid + 768] = f2b(acc[s][3]);
  }
}

// ---------------- PE gather -> inp1c[:,1152:1280] ----------------
__global__ void k_pegather(const int* __restrict__ dfi, const float* __restrict__ pe,
                           unsigned short* inp1c, int t0, int tbeg, int R) {
  int idx = blockIdx.x * 256 + threadIdx.x;
  if (idx >= R * 4096) return;
  int d = idx & 127, r = idx >> 7;
  int b = r & 31, ti = r >> 5;
  int t = tbeg + ti;
  int pos = dfi[b * 800 + t];
  inp1c[((size_t)(t - t0) * 32 + b) * 1280 + 1152 + d] = f2b(pe[pos * 128 + d]);
}

// ---------------- Wih1 fp32 -> bf16 (round-nearest), same [4096][1280] layout ----------------
__global__ void k_repackW(const float* __restrict__ Wih1, unsigned short* wbf) {
  int idx = blockIdx.x * 256 + threadIdx.x;          // one float4 per thread
  if (idx >= 1310720) return;
  float4 f = *(const float4*)(Wih1 + (size_t)idx * 4);
  union { unsigned short us[4]; unsigned long long q; } o;
  o.us[0] = f2b(f.x); o.us[1] = f2b(f.y); o.us[2] = f2b(f.z); o.us[3] = f2b(f.w);
  *(unsigned long long*)(wbf + (size_t)idx * 4) = o.q;
}

// ---------------- melpre[t][b][c] = ctx_pe . Wproj[c,1024:2048] + bproj[c] ----------------
__global__ __launch_bounds__(256) void k_melpre(const unsigned short* __restrict__ inp1c,
                                                const float* __restrict__ Wproj,
                                                const float* __restrict__ bproj,
                                                unsigned short* melpre, int t0, int tbeg) {
  extern __shared__ unsigned short ctx[];  // 32*1024 bf16
  int t = tbeg + blockIdx.x, tid = threadIdx.x;
  int tt = t - t0;
  for (int i = tid; i < 32768; i += 256)
    ctx[i] = inp1c[((size_t)tt * 32 + (i >> 10)) * 1280 + 256 + (i & 1023)];
  __syncthreads();
  if (tid < 240) {
    int c = tid % 80, bs = tid / 80;
    const float* w = Wproj + (size_t)c * 2048 + 1024;
    for (int b = bs; b < 32; b += 3) {
      float s = bproj[c];
      const unsigned short* x = ctx + b * 1024;
#pragma unroll 8
      for (int kk = 0; kk < 1024; ++kk) s += b2f(x[kk]) * w[kk];
      melpre[((size_t)t * 32 + b) * 80 + c] = f2b(s);
    }
  }
}

// ---------------- persistent cooperative decoder ----------------
struct DecArgs {
  const unsigned short* inp1c;
  const unsigned short* wbf;
  const float* Wih1;
  const float* Whh1; const float* Wih2; const float* Whh2;
  const float* bih1; const float* bhh1; const float* bih2; const float* bhh2;
  const float* Wproj; const float* bproj;
  const unsigned short* melpre;
  unsigned short* h1; unsigned short* h2; float* cst;
  unsigned int* cnt; float* out_mel;
  int k0, k1, useHi;
};

__global__ __launch_bounds__(512, 1) void k_decode(DecArgs A) {
  extern __shared__ char smem[];
  short* img       = (short*)smem;                       // 3 x 32 KB B-frag images
  float (*g1)[17]  = (float(*)[17])(smem + 98304);
  float (*g2a)[17] = (float(*)[17])(smem + 100480);
  float (*g2b)[17] = (float(*)[17])(smem + 102656);
  float (*c1)[4]   = (float(*)[4])(smem + 104832);
  float (*c2)[4]   = (float(*)[4])(smem + 105344);
  float* bias1     = (float*)(smem + 105856);
  float* bias2     = (float*)(smem + 105920);

  int wg = blockIdx.x, tid = threadIdx.x;
  int wid = tid >> 6, lane = tid & 63;
  int k0 = A.k0, k1 = A.k1;

  // repack recurrent weight B-frag images (round-nearest)
  for (int s = tid; s < 6144; s += 512) {
    int gi = s >> 11, r = s & 2047;
    int ks = r >> 6, l = r & 63;
    int nn = l & 15, kq = l >> 4;
    int row = (nn >> 2) * 1024 + wg * 4 + (nn & 3);
    const float* W = (gi == 0) ? A.Whh1 : (gi == 1) ? A.Wih2 : A.Whh2;
    const float* src = W + (size_t)row * 1024 + ks * 32 + kq * 8;
    union { unsigned short us[8]; bfrag8 v; } t_;
#pragma unroll
    for (int e = 0; e < 8; ++e) t_.us[e] = f2b(src[e]);
    ((bfrag8*)img)[s] = t_.v;
  }
  if (tid < 16) {
    int row = (tid >> 2) * 1024 + wg * 4 + (tid & 3);
    bias1[tid] = A.bih1[row] + A.bhh1[row];
    bias2[tid] = A.bih2[row] + A.bhh2[row];
  }
  if (tid < 128) {
    int b = tid >> 2, jj = tid & 3;
    c1[b][jj] = (k0 == 0) ? 0.f : A.cst[((size_t)wg * 32 + b) * 4 + jj];
  } else if (tid < 256) {
    int b = (tid - 128) >> 2, jj = tid & 3;
    c2[b][jj] = (k0 == 0) ? 0.f : A.cst[32768 + ((size_t)wg * 32 + b) * 4 + jj];
  }
  float bpr = (wg < 80) ? A.bproj[wg] : 0.f;
  __syncthreads();

  long totspin = 0;
  for (int k = k0; k < k1; ++k) {
    bool do1 = (k < 800);
    bool do2 = (k >= 1 && k <= 800);
    if (wid < 2) {
      if (do1) {
        int nn = lane & 15, kq = lane >> 4;
        int brow = wid * 16 + nn;
        int row = (nn >> 2) * 1024 + wg * 4 + (nn & 3);
        f32x4 a0 = {0.f,0.f,0.f,0.f}, a1 = {0.f,0.f,0.f,0.f};
        // ---- issue ALL h1 LLC loads up-front (latency hidden under the x-GEMM) ----
        const unsigned long long* hp = (const unsigned long long*)(A.h1 + ((k - 1) & 1) * 32768 + brow * 1024 + kq * 8);
        unsigned long long hr[64];
#pragma unroll
        for (int i = 0; i < 64; ++i)
          hr[i] = __hip_atomic_load(hp + (size_t)(i >> 1) * 8 + (i & 1), __ATOMIC_RELAXED, AGENT);
        // ---- x-GEMM (L2-resident operands) while h loads are in flight ----
        size_t tt = (size_t)(k - k0 + 2);
        const unsigned short* arow = A.inp1c + (tt * 32 + brow) * 1280 + kq * 8;
        if (A.useHi) {
          const unsigned short* wrow = A.wbf + (size_t)row * 1280 + kq * 8;
#pragma unroll 4
          for (int ks = 0; ks < 40; ks += 2) {
            bfrag8 aA = *(const bfrag8*)(arow + ks * 32);
            bfrag8 aB = *(const bfrag8*)(arow + ks * 32 + 32);
            bfrag8 b0 = *(const bfrag8*)(wrow + ks * 32);
            bfrag8 b1 = *(const bfrag8*)(wrow + ks * 32 + 32);
            a0 = __builtin_amdgcn_mfma_f32_16x16x32_bf16(aA, b0, a0, 0, 0, 0);
            a1 = __builtin_amdgcn_mfma_f32_16x16x32_bf16(aB, b1, a1, 0, 0, 0);
          }
        } else {
          const float* wsrc = A.Wih1 + (size_t)row * 1280 + kq * 8;
#pragma unroll 4
          for (int ks = 0; ks < 40; ks += 2) {
            bfrag8 aA = *(const bfrag8*)(arow + ks * 32);
            bfrag8 aB = *(const bfrag8*)(arow + ks * 32 + 32);
            union { unsigned short us[8]; bfrag8 v; } b0, b1;
            float4 f0 = *(const float4*)(wsrc + ks * 32);
            float4 f1 = *(const float4*)(wsrc + ks * 32 + 4);
            float4 f2 = *(const float4*)(wsrc + ks * 32 + 32);
            float4 f3 = *(const float4*)(wsrc + ks * 32 + 36);
            b0.us[0]=f2b(f0.x); b0.us[1]=f2b(f0.y); b0.us[2]=f2b(f0.z); b0.us[3]=f2b(f0.w);
            b0.us[4]=f2b(f1.x); b0.us[5]=f2b(f1.y); b0.us[6]=f2b(f1.z); b0.us[7]=f2b(f1.w);
            b1.us[0]=f2b(f2.x); b1.us[1]=f2b(f2.y); b1.us[2]=f2b(f2.z); b1.us[3]=f2b(f2.w);
            b1.us[4]=f2b(f3.x); b1.us[5]=f2b(f3.y); b1.us[6]=f2b(f3.z); b1.us[7]=f2b(f3.w);
            a0 = __builtin_amdgcn_mfma_f32_16x16x32_bf16(aA, b0.v, a0, 0, 0, 0);
            a1 = __builtin_amdgcn_mfma_f32_16x16x32_bf16(aB, b1.v, a1, 0, 0, 0);
          }
        }
        // ---- consume h fragments (single drain) ----
        const bfrag8* bp = (const bfrag8*)img + lane;
#pragma unroll
        for (int ks = 0; ks < 32; ks += 2) {
          union { unsigned long long q[2]; bfrag8 v; } aa, ab;
          aa.q[0] = hr[2 * ks];     aa.q[1] = hr[2 * ks + 1];
          ab.q[0] = hr[2 * ks + 2]; ab.q[1] = hr[2 * ks + 3];
          a0 = __builtin_amdgcn_mfma_f32_16x16x32_bf16(aa.v, bp[ks * 64], a0, 0, 0, 0);
          a1 = __builtin_amdgcn_mfma_f32_16x16x32_bf16(ab.v, bp[(ks + 1) * 64], a1, 0, 0, 0);
        }
        f32x4 acc = a0 + a1;
#pragma unroll
        for (int q = 0; q < 4; ++q) g1[wid * 16 + kq * 4 + q][nn] = acc[q];
      }
    } else if (wid < 6) {
      if (do2) {
        int mt, imgbase; const unsigned short* hb;
        if (wid < 4) { mt = wid - 2; imgbase = 2048; hb = A.h1 + ((k - 1) & 1) * 32768; }
        else         { mt = wid - 4; imgbase = 4096; hb = A.h2 + (k & 1) * 32768; }
        int nn = lane & 15, kq = lane >> 4;
        int brow = mt * 16 + nn;
        f32x4 a0 = {0.f,0.f,0.f,0.f}, a1 = {0.f,0.f,0.f,0.f};
        const unsigned long long* hp = (const unsigned long long*)(hb + brow * 1024 + kq * 8);
        unsigned long long hr[64];
#pragma unroll
        for (int i = 0; i < 64; ++i)
          hr[i] = __hip_atomic_load(hp + (size_t)(i >> 1) * 8 + (i & 1), __ATOMIC_RELAXED, AGENT);
        const bfrag8* bp = (const bfrag8*)img + imgbase + lane;
#pragma unroll
        for (int ks = 0; ks < 32; ks += 2) {
          union { unsigned long long q[2]; bfrag8 v; } aa, ab;
          aa.q[0] = hr[2 * ks];     aa.q[1] = hr[2 * ks + 1];
          ab.q[0] = hr[2 * ks + 2]; ab.q[1] = hr[2 * ks + 3];
          a0 = __builtin_amdgcn_mfma_f32_16x16x32_bf16(aa.v, bp[ks * 64], a0, 0, 0, 0);
          a1 = __builtin_amdgcn_mfma_f32_16x16x32_bf16(ab.v, bp[(ks + 1) * 64], a1, 0, 0, 0);
        }
        f32x4 acc = a0 + a1;
        float (*gb)[17] = (wid < 4) ? g2a : g2b;
#pragma unroll
        for (int q = 0; q < 4; ++q) gb[mt * 16 + kq * 4 + q][nn] = acc[q];
      }
    } else {
      if (k >= 2 && wg < 80) {
        int t = k - 2;
        int L = (wid - 6) * 64 + lane;
        int b = L >> 2, q = L & 3;
        const unsigned long long* hp = (const unsigned long long*)(A.h2 + (k & 1) * 32768 + b * 1024 + q * 256);
        const float* wp = A.Wproj + (size_t)wg * 2048 + q * 256;
        unsigned long long hr[64];
#pragma unroll
        for (int i = 0; i < 64; ++i)
          hr[i] = __hip_atomic_load(hp + i, __ATOMIC_RELAXED, AGENT);
        float s0 = 0.f, s1 = 0.f;
#pragma unroll 8
        for (int i = 0; i < 64; i += 2) {
          union { unsigned long long q; unsigned short u[4]; } a, b_;
          a.q = hr[i]; b_.q = hr[i + 1];
          const float* w0 = wp + i * 4;
          s0 += b2f(a.u[0])*w0[0] + b2f(a.u[1])*w0[1] + b2f(a.u[2])*w0[2] + b2f(a.u[3])*w0[3];
          s1 += b2f(b_.u[0])*w0[4] + b2f(b_.u[1])*w0[5] + b2f(b_.u[2])*w0[6] + b2f(b_.u[3])*w0[7];
        }
        if (!A.useHi) {            // LO tier: ctx half inline
          size_t tt = (size_t)(k - k0);
          const unsigned long long* xp = (const unsigned long long*)(A.inp1c + (tt * 32 + b) * 1280 + 256 + q * 256);
          const float* wc = wp + 1024;
#pragma unroll 8
          for (int i = 0; i < 64; i += 2) {
            unsigned long long v0 = xp[i];
            unsigned long long v1 = xp[i + 1];
            union { unsigned long long q; unsigned short u[4]; } a, b_;
            a.q = v0; b_.q = v1;
            const float* w0 = wc + i * 4;
            s0 += b2f(a.u[0])*w0[0] + b2f(a.u[1])*w0[1] + b2f(a.u[2])*w0[2] + b2f(a.u[3])*w0[3];
            s1 += b2f(b_.u[0])*w0[4] + b2f(b_.u[1])*w0[5] + b2f(b_.u[2])*w0[6] + b2f(b_.u[3])*w0[7];
          }
        }
        float s = s0 + s1;
        s += __shfl_xor(s, 1);
        s += __shfl_xor(s, 2);
        if (q == 0) {
          float add = A.useHi ? b2f(A.melpre[((size_t)t * 32 + b) * 80 + wg]) : bpr;
          A.out_mel[(size_t)b * 64000 + (size_t)wg * 800 + t] = s + add;   // fp32 output
        }
      }
    }
    __syncthreads();
    if (tid < 128) {
      if (do1) {
        int b = tid >> 2, jj = tid & 3;
        float gi = g1[b][jj]      + bias1[jj];
        float gf = g1[b][4 + jj]  + bias1[4 + jj];
        float gg = g1[b][8 + jj]  + bias1[8 + jj];
        float go = g1[b][12 + jj] + bias1[12 + jj];
        float c = c1[b][jj];
        float cn = sigf(gf) * c + sigf(gi) * tanhf(gg);
        c1[b][jj] = cn;
        float hn = sigf(go) * tanhf(cn);
        float ho = __shfl_xor(hn, 1);
        if ((jj & 1) == 0) {
          unsigned int pk = (unsigned int)f2b(hn) | ((unsigned int)f2b(ho) << 16);
          __hip_atomic_store((unsigned int*)(A.h1 + (k & 1) * 32768 + b * 1024 + wg * 4 + jj), pk,
                             __ATOMIC_RELAXED, AGENT);
        }
      }
    } else if (tid < 256) {
      if (do2) {
        int b = (tid - 128) >> 2, jj = tid & 3;
        float gi = g2a[b][jj]      + g2b[b][jj]      + bias2[jj];
        float gf = g2a[b][4 + jj]  + g2b[b][4 + jj]  + bias2[4 + jj];
        float gg = g2a[b][8 + jj]  + g2b[b][8 + jj]  + bias2[8 + jj];
        float go = g2a[b][12 + jj] + g2b[b][12 + jj] + bias2[12 + jj];
        float c = c2[b][jj];
        float cn = sigf(gf) * c + sigf(gi) * tanhf(gg);
        c2[b][jj] = cn;
        float hn = sigf(go) * tanhf(cn);
        float ho = __shfl_xor(hn, 1);
        if ((jj & 1) == 0) {
          unsigned int pk = (unsigned int)f2b(hn) | ((unsigned int)f2b(ho) << 16);
          __hip_atomic_store((unsigned int*)(A.h2 + ((k - 1) & 1) * 32768 + b * 1024 + wg * 4 + jj), pk,
                             __ATOMIC_RELAXED, AGENT);
        }
      }
    }
    __syncthreads();   // drains vmcnt(0): all h-stores of this WG are committed before the arrive-add below
    if (tid == 0) {
      asm volatile("s_waitcnt vmcnt(0)" ::: "memory");
      __hip_atomic_fetch_add(A.cnt + (wg & 15) * 16, 1u, __ATOMIC_RELAXED, AGENT);
    }
    if (tid < 16 && totspin >= 0) {
      unsigned int tgt = (unsigned int)(k + 1) * 16u;
      while (__hip_atomic_load(A.cnt + tid * 16, __ATOMIC_RELAXED, AGENT) < tgt) {
        __builtin_amdgcn_s_sleep(2);
        if (++totspin > (1l << 25)) {          // watchdog: record + free-run, never hang
          totspin = -1;
          __hip_atomic_fetch_add(A.cnt + 255, 1u, __ATOMIC_RELAXED, AGENT);
          break;
        }
      }
    }
    __syncthreads();
  }
  if (tid < 128) {
    int b = tid >> 2, jj = tid & 3;
    A.cst[((size_t)wg * 32 + b) * 4 + jj] = c1[b][jj];
  } else if (tid < 256) {
    int b = (tid - 128) >> 2, jj = tid & 3;
    A.cst[32768 + ((size_t)wg * 32 + b) * 4 + jj] = c2[b][jj];
  }
}

// ---------------- diagnostics (fp32) ----------------
__global__ void k_diag(float* out_mel, float wsmb) {
  out_mel[0] = 1000.f + wsmb;                 // ~1000+MB => ws too small
}
__global__ void k_verify(const unsigned int* cnt, float* out_mel) {
  unsigned int tot = 0;
  for (int i = 0; i < 16; ++i) tot += cnt[i * 16];
  unsigned int wd = cnt[255];
  if (wd)
    out_mel[0] = 5000.f + (float)(wd > 900u ? 900u : wd);      // ~5000+ => barrier desync
  else if (tot != 802u * 256u)
    out_mel[0] = 3000.f + (float)tot * (1.f / 256.f);          // ~3000+ => decode stalled
}

extern "C" void kernel_launch(void* const* d_in, const int* in_sizes, int n_in,
                              void* d_out, int out_size, void* d_ws, size_t ws_size,
                              hipStream_t stream) {
  const float* memory = (const float*)d_in[0];
  const float* dur    = (const float*)d_in[1];
  const int*   dfi    = (const int*)d_in[2];
  const float* range  = (const float*)d_in[3];
  const float* din    = (const float*)d_in[4];
  const float* Wp1    = (const float*)d_in[6];
  const float* Wp2    = (const float*)d_in[7];
  const float* Wih1   = (const float*)d_in[8];
  const float* Whh1   = (const float*)d_in[9];
  const float* bih1   = (const float*)d_in[10];
  const float* bhh1   = (const float*)d_in[11];
  const float* Wih2   = (const float*)d_in[12];
  const float* Whh2   = (const float*)d_in[13];
  const float* bih2   = (const float*)d_in[14];
  const float* bhh2   = (const float*)d_in[15];
  const float* Wproj  = (const float*)d_in[16];
  const float* bproj  = (const float*)d_in[17];
  const float* u1     = (const float*)d_in[18];
  const float* u2     = (const float*)d_in[19];

  char* ws = (char*)d_ws;
  unsigned int* cnt   = (unsigned int*)ws;
  float* cvec         = (float*)(ws + 4096);
  float* coef         = cvec + 8192;
  float* inv2         = coef + 8192;
  float* pe           = (float*)(ws + 102400);
  unsigned short* h1  = (unsigned short*)(ws + 153600);
  unsigned short* h2  = h1 + 65536;
  float* cst          = (float*)(ws + 415744);

  float* out_mel   = (float*)d_out;                         // fp32 outputs (reference dtype)
  float* out_align = out_mel + 2048000;

  // tier selection
  int TC, useHi;
  unsigned short* melpre = (unsigned short*)(ws + 720896);
  unsigned short* wbf    = (unsigned short*)(ws + 4849664);
  unsigned short* inp1c;
  if      (ws_size >= 16777216ull + 802ull * 81920ull) { TC = 800; useHi = 1; }
  else if (ws_size >= 16777216ull + 202ull * 81920ull) { TC = 200; useHi = 1; }
  else if (ws_size >= 16777216ull +  82ull * 81920ull) { TC = 80;  useHi = 1; }
  else if (ws_size >= 16777216ull +  42ull * 81920ull) { TC = 40;  useHi = 1; }
  else if (ws_size >=   720896ull +  42ull * 81920ull) { TC = 40;  useHi = 0; }
  else {
    k_diag<<<1, 1, 0, stream>>>(out_mel, (float)(ws_size >> 20));
    return;
  }
  inp1c = (unsigned short*)(ws + (useHi ? 16777216ull : 720896ull));

  hipFuncSetAttribute((const void*)k_decode, hipFuncAttributeMaxDynamicSharedMemorySize, 131072);
  hipFuncSetAttribute((const void*)k_melpre, hipFuncAttributeMaxDynamicSharedMemorySize, 98304);

  k_init<<<256, 256, 0, stream>>>((unsigned int*)(ws + 153600), cnt, pe);
  k_attn_prep<<<32, 256, 0, stream>>>(dur, range, cvec, coef, inv2);
  k_attn<<<dim3(800, 32), 256, 0, stream>>>(cvec, coef, inv2, out_align);
  if (useHi) k_repackW<<<5120, 256, 0, stream>>>(Wih1, wbf);

  DecArgs da[20];
  int nch = (800 + TC - 1) / TC;
  for (int c = 0; c < nch; ++c) {
    int k0 = c * TC;
    int k1 = (c == nch - 1) ? 802 : (c + 1) * TC;
    int t0 = k0 - 2;
    int tbeg = t0 < 0 ? 0 : t0;
    int tend = k1 < 800 ? k1 : 800;
    int R = tend - tbeg;
    k_prenet<<<R, 256, 0, stream>>>(din, u1, u2, Wp1, Wp2, inp1c, t0, tbeg);
    k_ctx<<<dim3((R + 15) / 16, 32), 256, 0, stream>>>(cvec, coef, inv2, memory, inp1c, t0, tbeg, tend);
    k_pegather<<<(R * 4096 + 255) / 256, 256, 0, stream>>>(dfi, pe, inp1c, t0, tbeg, R);
    if (useHi) k_melpre<<<R, 256, 65536, stream>>>(inp1c, Wproj, bproj, melpre, t0, tbeg);

    da[c] = DecArgs{ inp1c, wbf, Wih1, Whh1, Wih2, Whh2, bih1, bhh1, bih2, bhh2,
                     Wproj, bproj, melpre, h1, h2, cst, cnt, out_mel, k0, k1, useHi };
    void* kp[1] = { &da[c] };
    hipLaunchCooperativeKernel((const void*)k_decode, dim3(256), dim3(512), kp, 105984, stream);
  }
  k_verify<<<1, 1, 0, stream>>>(cnt, out_mel);
}

// Round 8
// 23893.115 us; speedup vs baseline: 1.2179x; 1.2179x over previous
//
#include <hip/hip_runtime.h>
#include <hip/hip_bf16.h>
#include <math.h>

typedef __attribute__((ext_vector_type(8))) short bfrag8;   // 8 x bf16
typedef __attribute__((ext_vector_type(4))) float f32x4;    // MFMA accumulator
#define AGENT __HIP_MEMORY_SCOPE_AGENT

static __device__ __forceinline__ float b2f(unsigned short u) {
  union { unsigned int i; float f; } v; v.i = ((unsigned int)u) << 16; return v.f;
}
static __device__ __forceinline__ unsigned short f2b(float f) {
  union { float f; unsigned int i; } v; v.f = f;
  unsigned int i = v.i;
  return (unsigned short)((i + 0x7FFFu + ((i >> 16) & 1u)) >> 16);
}
static __device__ __forceinline__ float sigf(float x) { return 1.f / (1.f + __expf(-x)); }

// ---------------- workspace layout (bytes) ----------------
// cnt   [0,1024)        barrier lines (16 x 64B) + cnt[255] = watchdog flag
// scan  [4096,102400)   cvec/coef/inv2 (3 x 8192 fp32)
// pe    [102400,153600) 100x128 fp32
// h1    [153600,284672) 2 slots x 32x1024 bf16
// h2    [284672,415744)
// cst   [415744,677888) c1,c2 save: 2 x 256x32x4 fp32
// LO:  inp1c @ 720896
// HI:  melpre @ 720896 (4,096,000) ; wbf @ 4,849,664 (10,485,760) ; inp1c @ 16,777,216

// ---------------- init ----------------
__global__ void k_init(unsigned int* hzero, unsigned int* cnt, float* pe) {
  int idx = blockIdx.x * 256 + threadIdx.x;
  if (idx < 256) cnt[idx] = 0u;
  if (idx < 65536) hzero[idx] = 0u;                     // h1+h2 both slots
  if (idx < 6400) {
    int p = idx >> 6, i = idx & 63;
    float freq = __expf(-(float)(2 * i) * 0.0719557842162201f); // ln(10000)/128
    float a = (float)p * freq;
    pe[p * 128 + 2 * i]     = sinf(a);
    pe[p * 128 + 2 * i + 1] = cosf(a);
  }
}

// ---------------- prenet -> inp1c[:, 0:256] ----------------
__global__ __launch_bounds__(256) void k_prenet(const float* __restrict__ din,
                                                const float* __restrict__ u1,
                                                const float* __restrict__ u2,
                                                const float* __restrict__ Wp1,
                                                const float* __restrict__ Wp2,
                                                unsigned short* inp1c, int t0, int tbeg) {
  __shared__ float dec[2560];
  __shared__ float X1[8192];
  int t = tbeg + blockIdx.x, tid = threadIdx.x;
  int tt = t - t0;
  for (int i = tid; i < 2560; i += 256) {
    int b = i / 80, f = i % 80;
    dec[i] = (t == 0) ? 0.f : din[((size_t)b * 80 + f) * 800 + (t - 1)];
  }
  __syncthreads();
  int n = tid;
  for (int b = 0; b < 32; ++b) {
    float s = 0.f;
    const float* w = Wp1 + n * 80;
    const float* d = dec + b * 80;
#pragma unroll 8
    for (int f = 0; f < 80; ++f) s += d[f] * w[f];
    s = fmaxf(s, 0.f);
    float m = (u1[((size_t)t * 32 + b) * 256 + n] >= 0.5f) ? 2.f : 0.f;
    X1[b * 256 + n] = s * m;
  }
  __syncthreads();
  for (int b = 0; b < 32; ++b) {
    float s = 0.f;
    const float* w = Wp2 + n * 256;
    const float* x = X1 + b * 256;
#pragma unroll 8
    for (int kk = 0; kk < 256; ++kk) s += x[kk] * w[kk];
    s = fmaxf(s, 0.f);
    float m = (u2[((size_t)t * 32 + b) * 256 + n] >= 0.5f) ? 2.f : 0.f;
    inp1c[((size_t)tt * 32 + b) * 1280 + n] = f2b(s * m);
  }
}

// ---------------- attention precompute ----------------
__global__ __launch_bounds__(256) void k_attn_prep(const float* __restrict__ dur,
                                                   const float* __restrict__ range,
                                                   float* cvec, float* coef, float* inv2) {
  __shared__ float s[256];
  int b = blockIdx.x, e = threadIdx.x;
  float d = dur[b * 256 + e];
  s[e] = d;
  __syncthreads();
  for (int off = 1; off < 256; off <<= 1) {
    float v = (e >= off) ? s[e - off] : 0.f;
    __syncthreads();
    s[e] = s[e] + v;
    __syncthreads();
  }
  float c = s[e] - 0.5f * d;
  float sg = range[b * 256 + e] + 1e-5f;
  cvec[b * 256 + e] = c;
  coef[b * 256 + e] = rsqrtf(6.283185307179586f * sg * sg);
  inv2[b * 256 + e] = 1.f / (2.f * sg * sg);
}

// ---------------- alignments output (fp32) ----------------
__global__ __launch_bounds__(256) void k_attn(const float* __restrict__ cvec,
                                              const float* __restrict__ coef,
                                              const float* __restrict__ inv2,
                                              float* out_align) {
  __shared__ float red[4];
  int t = blockIdx.x, b = blockIdx.y, e = threadIdx.x;
  float dt = (float)t - cvec[b * 256 + e];
  float p = coef[b * 256 + e] * __expf(-dt * dt * inv2[b * 256 + e]) + 1e-5f;
  float s = p;
#pragma unroll
  for (int o = 1; o < 64; o <<= 1) s += __shfl_xor(s, o);
  if ((e & 63) == 0) red[e >> 6] = s;
  __syncthreads();
  float tot = red[0] + red[1] + red[2] + red[3];
  out_align[((size_t)b * 800 + t) * 256 + e] = p / tot;
}

// ---------------- context -> inp1c[:,256:1152] ----------------
__global__ __launch_bounds__(256) void k_ctx(const float* __restrict__ cvec,
                                             const float* __restrict__ coef,
                                             const float* __restrict__ inv2,
                                             const float* __restrict__ mem,
                                             unsigned short* inp1c,
                                             int t0, int tbeg, int tend) {
  __shared__ float wl[4096];
  __shared__ float rinv[16];
  int b = blockIdx.y, tB = tbeg + blockIdx.x * 16, tid = threadIdx.x;
  int nt = tend - tB; if (nt > 16) nt = 16;
  float cv = cvec[b * 256 + tid], co = coef[b * 256 + tid], iv = inv2[b * 256 + tid];
  for (int s = 0; s < nt; ++s) {
    float d = (float)(tB + s) - cv;
    wl[s * 256 + tid] = co * __expf(-d * d * iv) + 1e-5f;
  }
  for (int s = nt; s < 16; ++s) wl[s * 256 + tid] = 0.f;
  __syncthreads();
  int wv = tid >> 6, ln = tid & 63;
  for (int s = wv; s < nt; s += 4) {
    float x = wl[s * 256 + ln] + wl[s * 256 + 64 + ln] + wl[s * 256 + 128 + ln] + wl[s * 256 + 192 + ln];
#pragma unroll
    for (int o = 1; o < 64; o <<= 1) x += __shfl_xor(x, o);
    if (ln == 0) rinv[s] = 1.f / x;
  }
  __syncthreads();
  for (int s = 0; s < nt; ++s) wl[s * 256 + tid] *= rinv[s];
  __syncthreads();
  float acc[16][4];
#pragma unroll
  for (int s = 0; s < 16; ++s) { acc[s][0] = 0.f; acc[s][1] = 0.f; acc[s][2] = 0.f; acc[s][3] = 0.f; }
  for (int e = 0; e < 256; ++e) {
    const float* mrow = mem + ((size_t)b * 256 + e) * 896;
    float m0 = mrow[tid], m1 = mrow[tid + 256], m2 = mrow[tid + 512];
    float m3 = (tid < 128) ? mrow[tid + 768] : 0.f;
#pragma unroll
    for (int s = 0; s < 16; ++s) {
      float w = wl[s * 256 + e];
      acc[s][0] += w * m0; acc[s][1] += w * m1; acc[s][2] += w * m2; acc[s][3] += w * m3;
    }
  }
  for (int s = 0; s < nt; ++s) {
    size_t base = ((size_t)(tB - t0 + s) * 32 + b) * 1280 + 256;
    inp1c[base + tid]       = f2b(acc[s][0]);
    inp1c[base + tid + 256] = f2b(acc[s][1]);
    inp1c[base + tid + 512] = f2b(acc[s][2]);
    if (tid < 128) inp1c[base + tid + 768] = f2b(acc[s][3]);
  }
}

// ---------------- PE gather -> inp1c[:,1152:1280] ----------------
__global__ void k_pegather(const int* __restrict__ dfi, const float* __restrict__ pe,
                           unsigned short* inp1c, int t0, int tbeg, int R) {
  int idx = blockIdx.x * 256 + threadIdx.x;
  if (idx >= R * 4096) return;
  int d = idx & 127, r = idx >> 7;
  int b = r & 31, ti = r >> 5;
  int t = tbeg + ti;
  int pos = dfi[b * 800 + t];
  inp1c[((size_t)(t - t0) * 32 + b) * 1280 + 1152 + d] = f2b(pe[pos * 128 + d]);
}

// ---------------- Wih1 fp32 -> bf16 (round-nearest), same [4096][1280] layout ----------------
__global__ void k_repackW(const float* __restrict__ Wih1, unsigned short* wbf) {
  int idx = blockIdx.x * 256 + threadIdx.x;          // one float4 per thread
  if (idx >= 1310720) return;
  float4 f = *(const float4*)(Wih1 + (size_t)idx * 4);
  union { unsigned short us[4]; unsigned long long q; } o;
  o.us[0] = f2b(f.x); o.us[1] = f2b(f.y); o.us[2] = f2b(f.z); o.us[3] = f2b(f.w);
  *(unsigned long long*)(wbf + (size_t)idx * 4) = o.q;
}

// ---------------- melpre[t][b][c] = ctx_pe . Wproj[c,1024:2048] + bproj[c] ----------------
__global__ __launch_bounds__(256) void k_melpre(const unsigned short* __restrict__ inp1c,
                                                const float* __restrict__ Wproj,
                                                const float* __restrict__ bproj,
                                                unsigned short* melpre, int t0, int tbeg) {
  extern __shared__ unsigned short ctx[];  // 32*1024 bf16
  int t = tbeg + blockIdx.x, tid = threadIdx.x;
  int tt = t - t0;
  for (int i = tid; i < 32768; i += 256)
    ctx[i] = inp1c[((size_t)tt * 32 + (i >> 10)) * 1280 + 256 + (i & 1023)];
  __syncthreads();
  if (tid < 240) {
    int c = tid % 80, bs = tid / 80;
    const float* w = Wproj + (size_t)c * 2048 + 1024;
    for (int b = bs; b < 32; b += 3) {
      float s = bproj[c];
      const unsigned short* x = ctx + b * 1024;
#pragma unroll 8
      for (int kk = 0; kk < 1024; ++kk) s += b2f(x[kk]) * w[kk];
      melpre[((size_t)t * 32 + b) * 80 + c] = f2b(s);
    }
  }
}

// ----- software-pipelined coherent h-load chunks (16 qwords = 8 ks steps each) -----
#define LOAD_H_CHUNK(dst, c)                                                          \
  { _Pragma("unroll") for (int j_ = 0; j_ < 8; ++j_) {                                \
      dst[2*j_]   = __hip_atomic_load(hp + (size_t)((c)*8 + j_)*8,     __ATOMIC_RELAXED, AGENT); \
      dst[2*j_+1] = __hip_atomic_load(hp + (size_t)((c)*8 + j_)*8 + 1, __ATOMIC_RELAXED, AGENT); } }

#define MFMA_H_CHUNK(src, c)                                                          \
  { _Pragma("unroll") for (int j_ = 0; j_ < 8; j_ += 2) {                             \
      union { unsigned long long q[2]; bfrag8 v; } aa_, ab_;                          \
      aa_.q[0] = src[2*j_];   aa_.q[1] = src[2*j_+1];                                 \
      ab_.q[0] = src[2*j_+2]; ab_.q[1] = src[2*j_+3];                                 \
      a0 = __builtin_amdgcn_mfma_f32_16x16x32_bf16(aa_.v, bp[((c)*8+j_)*64],   a0, 0, 0, 0); \
      a1 = __builtin_amdgcn_mfma_f32_16x16x32_bf16(ab_.v, bp[((c)*8+j_+1)*64], a1, 0, 0, 0); } }

#define LOAD_MEL_CHUNK(dst, c)                                                        \
  { _Pragma("unroll") for (int j_ = 0; j_ < 16; ++j_)                                 \
      dst[j_] = __hip_atomic_load(hp + (size_t)((c)*16 + j_), __ATOMIC_RELAXED, AGENT); }

#define MEL_CONSUME_CHUNK(src, c)                                                     \
  { _Pragma("unroll") for (int j_ = 0; j_ < 16; j_ += 2) {                            \
      union { unsigned long long q; unsigned short u[4]; } a_, b2_;                   \
      a_.q = src[j_]; b2_.q = src[j_+1];                                              \
      const float* w0_ = wp + ((c)*16 + j_) * 4;                                      \
      s0 += b2f(a_.u[0])*w0_[0] + b2f(a_.u[1])*w0_[1] + b2f(a_.u[2])*w0_[2] + b2f(a_.u[3])*w0_[3]; \
      s1 += b2f(b2_.u[0])*w0_[4] + b2f(b2_.u[1])*w0_[5] + b2f(b2_.u[2])*w0_[6] + b2f(b2_.u[3])*w0_[7]; } }

// ---------------- persistent cooperative decoder ----------------
struct DecArgs {
  const unsigned short* inp1c;
  const unsigned short* wbf;
  const float* Wih1;
  const float* Whh1; const float* Wih2; const float* Whh2;
  const float* bih1; const float* bhh1; const float* bih2; const float* bhh2;
  const float* Wproj; const float* bproj;
  const unsigned short* melpre;
  unsigned short* h1; unsigned short* h2; float* cst;
  unsigned int* cnt; float* out_mel;
  int k0, k1, useHi;
};

__global__ __launch_bounds__(512, 1) void k_decode(DecArgs A) {
  extern __shared__ char smem[];
  short* img       = (short*)smem;                       // 3 x 32 KB B-frag images
  float (*g1)[17]  = (float(*)[17])(smem + 98304);
  float (*g2a)[17] = (float(*)[17])(smem + 100480);
  float (*g2b)[17] = (float(*)[17])(smem + 102656);
  float (*c1)[4]   = (float(*)[4])(smem + 104832);
  float (*c2)[4]   = (float(*)[4])(smem + 105344);
  float* bias1     = (float*)(smem + 105856);
  float* bias2     = (float*)(smem + 105920);

  int wg = blockIdx.x, tid = threadIdx.x;
  int wid = tid >> 6, lane = tid & 63;
  int k0 = A.k0, k1 = A.k1;

  // repack recurrent weight B-frag images (round-nearest)
  for (int s = tid; s < 6144; s += 512) {
    int gi = s >> 11, r = s & 2047;
    int ks = r >> 6, l = r & 63;
    int nn = l & 15, kq = l >> 4;
    int row = (nn >> 2) * 1024 + wg * 4 + (nn & 3);
    const float* W = (gi == 0) ? A.Whh1 : (gi == 1) ? A.Wih2 : A.Whh2;
    const float* src = W + (size_t)row * 1024 + ks * 32 + kq * 8;
    union { unsigned short us[8]; bfrag8 v; } t_;
#pragma unroll
    for (int e = 0; e < 8; ++e) t_.us[e] = f2b(src[e]);
    ((bfrag8*)img)[s] = t_.v;
  }
  if (tid < 16) {
    int row = (tid >> 2) * 1024 + wg * 4 + (tid & 3);
    bias1[tid] = A.bih1[row] + A.bhh1[row];
    bias2[tid] = A.bih2[row] + A.bhh2[row];
  }
  if (tid < 128) {
    int b = tid >> 2, jj = tid & 3;
    c1[b][jj] = (k0 == 0) ? 0.f : A.cst[((size_t)wg * 32 + b) * 4 + jj];
  } else if (tid < 256) {
    int b = (tid - 128) >> 2, jj = tid & 3;
    c2[b][jj] = (k0 == 0) ? 0.f : A.cst[32768 + ((size_t)wg * 32 + b) * 4 + jj];
  }
  float bpr = (wg < 80) ? A.bproj[wg] : 0.f;
  __syncthreads();

  long totspin = 0;
  for (int k = k0; k < k1; ++k) {
    bool do1 = (k < 800);
    bool do2 = (k >= 1 && k <= 800);
    if (wid < 2) {
      if (do1) {
        int nn = lane & 15, kq = lane >> 4;
        int brow = wid * 16 + nn;
        int row = (nn >> 2) * 1024 + wg * 4 + (nn & 3);
        f32x4 a0 = {0.f,0.f,0.f,0.f}, a1 = {0.f,0.f,0.f,0.f};
        const unsigned long long* hp = (const unsigned long long*)(A.h1 + ((k - 1) & 1) * 32768 + brow * 1024 + kq * 8);
        const bfrag8* bp = (const bfrag8*)img + lane;
        unsigned long long hA[16], hB[16];
        LOAD_H_CHUNK(hA, 0);                 // 16 coherent loads in flight
        // ---- x-GEMM (L2-resident operands) while chunk 0 is in flight ----
        size_t tt = (size_t)(k - k0 + 2);
        const unsigned short* arow = A.inp1c + (tt * 32 + brow) * 1280 + kq * 8;
        if (A.useHi) {
          const unsigned short* wrow = A.wbf + (size_t)row * 1280 + kq * 8;
#pragma unroll 4
          for (int ks = 0; ks < 40; ks += 2) {
            bfrag8 aA = *(const bfrag8*)(arow + ks * 32);
            bfrag8 aB = *(const bfrag8*)(arow + ks * 32 + 32);
            bfrag8 b0 = *(const bfrag8*)(wrow + ks * 32);
            bfrag8 b1 = *(const bfrag8*)(wrow + ks * 32 + 32);
            a0 = __builtin_amdgcn_mfma_f32_16x16x32_bf16(aA, b0, a0, 0, 0, 0);
            a1 = __builtin_amdgcn_mfma_f32_16x16x32_bf16(aB, b1, a1, 0, 0, 0);
          }
        } else {
          const float* wsrc = A.Wih1 + (size_t)row * 1280 + kq * 8;
#pragma unroll 4
          for (int ks = 0; ks < 40; ks += 2) {
            bfrag8 aA = *(const bfrag8*)(arow + ks * 32);
            bfrag8 aB = *(const bfrag8*)(arow + ks * 32 + 32);
            union { unsigned short us[8]; bfrag8 v; } b0, b1;
            float4 f0 = *(const float4*)(wsrc + ks * 32);
            float4 f1 = *(const float4*)(wsrc + ks * 32 + 4);
            float4 f2 = *(const float4*)(wsrc + ks * 32 + 32);
            float4 f3 = *(const float4*)(wsrc + ks * 32 + 36);
            b0.us[0]=f2b(f0.x); b0.us[1]=f2b(f0.y); b0.us[2]=f2b(f0.z); b0.us[3]=f2b(f0.w);
            b0.us[4]=f2b(f1.x); b0.us[5]=f2b(f1.y); b0.us[6]=f2b(f1.z); b0.us[7]=f2b(f1.w);
            b1.us[0]=f2b(f2.x); b1.us[1]=f2b(f2.y); b1.us[2]=f2b(f2.z); b1.us[3]=f2b(f2.w);
            b1.us[4]=f2b(f3.x); b1.us[5]=f2b(f3.y); b1.us[6]=f2b(f3.z); b1.us[7]=f2b(f3.w);
            a0 = __builtin_amdgcn_mfma_f32_16x16x32_bf16(aA, b0.v, a0, 0, 0, 0);
            a1 = __builtin_amdgcn_mfma_f32_16x16x32_bf16(aB, b1.v, a1, 0, 0, 0);
          }
        }
        // ---- pipelined h-MFMA: 16 loads always in flight ----
        LOAD_H_CHUNK(hB, 1);
        MFMA_H_CHUNK(hA, 0);
        LOAD_H_CHUNK(hA, 2);
        MFMA_H_CHUNK(hB, 1);
        LOAD_H_CHUNK(hB, 3);
        MFMA_H_CHUNK(hA, 2);
        MFMA_H_CHUNK(hB, 3);
        f32x4 acc = a0 + a1;
#pragma unroll
        for (int q = 0; q < 4; ++q) g1[wid * 16 + kq * 4 + q][nn] = acc[q];
      }
    } else if (wid < 6) {
      if (do2) {
        int mt, imgbase; const unsigned short* hb;
        if (wid < 4) { mt = wid - 2; imgbase = 2048; hb = A.h1 + ((k - 1) & 1) * 32768; }
        else         { mt = wid - 4; imgbase = 4096; hb = A.h2 + (k & 1) * 32768; }
        int nn = lane & 15, kq = lane >> 4;
        int brow = mt * 16 + nn;
        f32x4 a0 = {0.f,0.f,0.f,0.f}, a1 = {0.f,0.f,0.f,0.f};
        const unsigned long long* hp = (const unsigned long long*)(hb + brow * 1024 + kq * 8);
        const bfrag8* bp = (const bfrag8*)img + imgbase + lane;
        unsigned long long hA[16], hB[16];
        LOAD_H_CHUNK(hA, 0);
        LOAD_H_CHUNK(hB, 1);
        MFMA_H_CHUNK(hA, 0);
        LOAD_H_CHUNK(hA, 2);
        MFMA_H_CHUNK(hB, 1);
        LOAD_H_CHUNK(hB, 3);
        MFMA_H_CHUNK(hA, 2);
        MFMA_H_CHUNK(hB, 3);
        f32x4 acc = a0 + a1;
        float (*gb)[17] = (wid < 4) ? g2a : g2b;
#pragma unroll
        for (int q = 0; q < 4; ++q) gb[mt * 16 + kq * 4 + q][nn] = acc[q];
      }
    } else {
      if (k >= 2 && wg < 80) {
        int t = k - 2;
        int L = (wid - 6) * 64 + lane;
        int b = L >> 2, q = L & 3;
        const unsigned long long* hp = (const unsigned long long*)(A.h2 + (k & 1) * 32768 + b * 1024 + q * 256);
        const float* wp = A.Wproj + (size_t)wg * 2048 + q * 256;
        float s0 = 0.f, s1 = 0.f;
        unsigned long long mA[16], mB[16];
        LOAD_MEL_CHUNK(mA, 0);
        LOAD_MEL_CHUNK(mB, 1);
        MEL_CONSUME_CHUNK(mA, 0);
        LOAD_MEL_CHUNK(mA, 2);
        MEL_CONSUME_CHUNK(mB, 1);
        LOAD_MEL_CHUNK(mB, 3);
        MEL_CONSUME_CHUNK(mA, 2);
        MEL_CONSUME_CHUNK(mB, 3);
        if (!A.useHi) {            // LO tier: ctx half inline
          size_t tt = (size_t)(k - k0);
          const unsigned long long* xp = (const unsigned long long*)(A.inp1c + (tt * 32 + b) * 1280 + 256 + q * 256);
          const float* wc = wp + 1024;
#pragma unroll 8
          for (int i = 0; i < 64; i += 2) {
            unsigned long long v0 = xp[i];
            unsigned long long v1 = xp[i + 1];
            union { unsigned long long q; unsigned short u[4]; } a, b_;
            a.q = v0; b_.q = v1;
            const float* w0 = wc + i * 4;
            s0 += b2f(a.u[0])*w0[0] + b2f(a.u[1])*w0[1] + b2f(a.u[2])*w0[2] + b2f(a.u[3])*w0[3];
            s1 += b2f(b_.u[0])*w0[4] + b2f(b_.u[1])*w0[5] + b2f(b_.u[2])*w0[6] + b2f(b_.u[3])*w0[7];
          }
        }
        float s = s0 + s1;
        s += __shfl_xor(s, 1);
        s += __shfl_xor(s, 2);
        if (q == 0) {
          float add = A.useHi ? b2f(A.melpre[((size_t)t * 32 + b) * 80 + wg]) : bpr;
          A.out_mel[(size_t)b * 64000 + (size_t)wg * 800 + t] = s + add;   // fp32 output
        }
      }
    }
    __syncthreads();
    if (tid < 128) {
      if (do1) {
        int b = tid >> 2, jj = tid & 3;
        float gi = g1[b][jj]      + bias1[jj];
        float gf = g1[b][4 + jj]  + bias1[4 + jj];
        float gg = g1[b][8 + jj]  + bias1[8 + jj];
        float go = g1[b][12 + jj] + bias1[12 + jj];
        float c = c1[b][jj];
        float cn = sigf(gf) * c + sigf(gi) * tanhf(gg);
        c1[b][jj] = cn;
        float hn = sigf(go) * tanhf(cn);
        float ho = __shfl_xor(hn, 1);
        if ((jj & 1) == 0) {
          unsigned int pk = (unsigned int)f2b(hn) | ((unsigned int)f2b(ho) << 16);
          __hip_atomic_store((unsigned int*)(A.h1 + (k & 1) * 32768 + b * 1024 + wg * 4 + jj), pk,
                             __ATOMIC_RELAXED, AGENT);
        }
      }
    } else if (tid < 256) {
      if (do2) {
        int b = (tid - 128) >> 2, jj = tid & 3;
        float gi = g2a[b][jj]      + g2b[b][jj]      + bias2[jj];
        float gf = g2a[b][4 + jj]  + g2b[b][4 + jj]  + bias2[4 + jj];
        float gg = g2a[b][8 + jj]  + g2b[b][8 + jj]  + bias2[8 + jj];
        float go = g2a[b][12 + jj] + g2b[b][12 + jj] + bias2[12 + jj];
        float c = c2[b][jj];
        float cn = sigf(gf) * c + sigf(gi) * tanhf(gg);
        c2[b][jj] = cn;
        float hn = sigf(go) * tanhf(cn);
        float ho = __shfl_xor(hn, 1);
        if ((jj & 1) == 0) {
          unsigned int pk = (unsigned int)f2b(hn) | ((unsigned int)f2b(ho) << 16);
          __hip_atomic_store((unsigned int*)(A.h2 + ((k - 1) & 1) * 32768 + b * 1024 + wg * 4 + jj), pk,
                             __ATOMIC_RELAXED, AGENT);
        }
      }
    }
    __syncthreads();   // drains vmcnt(0): all h-stores of this WG are committed before the arrive-add below
    if (tid == 0) {
      asm volatile("s_waitcnt vmcnt(0)" ::: "memory");
      __hip_atomic_fetch_add(A.cnt + (wg & 15) * 16, 1u, __ATOMIC_RELAXED, AGENT);
    }
    if (tid < 16 && totspin >= 0) {
      unsigned int tgt = (unsigned int)(k + 1) * 16u;
      while (__hip_atomic_load(A.cnt + tid * 16, __ATOMIC_RELAXED, AGENT) < tgt) {
        __builtin_amdgcn_s_sleep(2);
        if (++totspin > (1l << 25)) {          // watchdog: record + free-run, never hang
          totspin = -1;
          __hip_atomic_fetch_add(A.cnt + 255, 1u, __ATOMIC_RELAXED, AGENT);
          break;
        }
      }
    }
    __syncthreads();
  }
  if (tid < 128) {
    int b = tid >> 2, jj = tid & 3;
    A.cst[((size_t)wg * 32 + b) * 4 + jj] = c1[b][jj];
  } else if (tid < 256) {
    int b = (tid - 128) >> 2, jj = tid & 3;
    A.cst[32768 + ((size_t)wg * 32 + b) * 4 + jj] = c2[b][jj];
  }
}

// ---------------- diagnostics (fp32) ----------------
__global__ void k_diag(float* out_mel, float wsmb) {
  out_mel[0] = 1000.f + wsmb;                 // ~1000+MB => ws too small
}
__global__ void k_verify(const unsigned int* cnt, float* out_mel) {
  unsigned int tot = 0;
  for (int i = 0; i < 16; ++i) tot += cnt[i * 16];
  unsigned int wd = cnt[255];
  if (wd)
    out_mel[0] = 5000.f + (float)(wd > 900u ? 900u : wd);      // ~5000+ => barrier desync
  else if (tot != 802u * 256u)
    out_mel[0] = 3000.f + (float)tot * (1.f / 256.f);          // ~3000+ => decode stalled
}

extern "C" void kernel_launch(void* const* d_in, const int* in_sizes, int n_in,
                              void* d_out, int out_size, void* d_ws, size_t ws_size,
                              hipStream_t stream) {
  const float* memory = (const float*)d_in[0];
  const float* dur    = (const float*)d_in[1];
  const int*   dfi    = (const int*)d_in[2];
  const float* range  = (const float*)d_in[3];
  const float* din    = (const float*)d_in[4];
  const float* Wp1    = (const float*)d_in[6];
  const float* Wp2    = (const float*)d_in[7];
  const float* Wih1   = (const float*)d_in[8];
  const float* Whh1   = (const float*)d_in[9];
  const float* bih1   = (const float*)d_in[10];
  const float* bhh1   = (const float*)d_in[11];
  const float* Wih2   = (const float*)d_in[12];
  const float* Whh2   = (const float*)d_in[13];
  const float* bih2   = (const float*)d_in[14];
  const float* bhh2   = (const float*)d_in[15];
  const float* Wproj  = (const float*)d_in[16];
  const float* bproj  = (const float*)d_in[17];
  const float* u1     = (const float*)d_in[18];
  const float* u2     = (const float*)d_in[19];

  char* ws = (char*)d_ws;
  unsigned int* cnt   = (unsigned int*)ws;
  float* cvec         = (float*)(ws + 4096);
  float* coef         = cvec + 8192;
  float* inv2         = coef + 8192;
  float* pe           = (float*)(ws + 102400);
  unsigned short* h1  = (unsigned short*)(ws + 153600);
  unsigned short* h2  = h1 + 65536;
  float* cst          = (float*)(ws + 415744);

  float* out_mel   = (float*)d_out;                         // fp32 outputs (reference dtype)
  float* out_align = out_mel + 2048000;

  // tier selection
  int TC, useHi;
  unsigned short* melpre = (unsigned short*)(ws + 720896);
  unsigned short* wbf    = (unsigned short*)(ws + 4849664);
  unsigned short* inp1c;
  if      (ws_size >= 16777216ull + 802ull * 81920ull) { TC = 800; useHi = 1; }
  else if (ws_size >= 16777216ull + 202ull * 81920ull) { TC = 200; useHi = 1; }
  else if (ws_size >= 16777216ull +  82ull * 81920ull) { TC = 80;  useHi = 1; }
  else if (ws_size >= 16777216ull +  42ull * 81920ull) { TC = 40;  useHi = 1; }
  else if (ws_size >=   720896ull +  42ull * 81920ull) { TC = 40;  useHi = 0; }
  else {
    k_diag<<<1, 1, 0, stream>>>(out_mel, (float)(ws_size >> 20));
    return;
  }
  inp1c = (unsigned short*)(ws + (useHi ? 16777216ull : 720896ull));

  hipFuncSetAttribute((const void*)k_decode, hipFuncAttributeMaxDynamicSharedMemorySize, 131072);
  hipFuncSetAttribute((const void*)k_melpre, hipFuncAttributeMaxDynamicSharedMemorySize, 98304);

  k_init<<<256, 256, 0, stream>>>((unsigned int*)(ws + 153600), cnt, pe);
  k_attn_prep<<<32, 256, 0, stream>>>(dur, range, cvec, coef, inv2);
  k_attn<<<dim3(800, 32), 256, 0, stream>>>(cvec, coef, inv2, out_align);
  if (useHi) k_repackW<<<5120, 256, 0, stream>>>(Wih1, wbf);

  DecArgs da[20];
  int nch = (800 + TC - 1) / TC;
  for (int c = 0; c < nch; ++c) {
    int k0 = c * TC;
    int k1 = (c == nch - 1) ? 802 : (c + 1) * TC;
    int t0 = k0 - 2;
    int tbeg = t0 < 0 ? 0 : t0;
    int tend = k1 < 800 ? k1 : 800;
    int R = tend - tbeg;
    k_prenet<<<R, 256, 0, stream>>>(din, u1, u2, Wp1, Wp2, inp1c, t0, tbeg);
    k_ctx<<<dim3((R + 15) / 16, 32), 256, 0, stream>>>(cvec, coef, inv2, memory, inp1c, t0, tbeg, tend);
    k_pegather<<<(R * 4096 + 255) / 256, 256, 0, stream>>>(dfi, pe, inp1c, t0, tbeg, R);
    if (useHi) k_melpre<<<R, 256, 65536, stream>>>(inp1c, Wproj, bproj, melpre, t0, tbeg);

    da[c] = DecArgs{ inp1c, wbf, Wih1, Whh1, Wih2, Whh2, bih1, bhh1, bih2, bhh2,
                     Wproj, bproj, melpre, h1, h2, cst, cnt, out_mel, k0, k1, useHi };
    void* kp[1] = { &da[c] };
    hipLaunchCooperativeKernel((const void*)k_decode, dim3(256), dim3(512), kp, 105984, stream);
  }
  k_verify<<<1, 1, 0, stream>>>(cnt, out_mel);
}

// Round 9
// 22342.123 us; speedup vs baseline: 1.3024x; 1.0694x over previous
//
#include <hip/hip_runtime.h>
#include <hip/hip_bf16.h>
#include <math.h>

typedef __attribute__((ext_vector_type(8))) short bfrag8;   // 8 x bf16
typedef __attribute__((ext_vector_type(4))) float f32x4;    // MFMA accumulator
#define AGENT __HIP_MEMORY_SCOPE_AGENT

static __device__ __forceinline__ float b2f(unsigned short u) {
  union { unsigned int i; float f; } v; v.i = ((unsigned int)u) << 16; return v.f;
}
static __device__ __forceinline__ unsigned short f2b(float f) {
  union { float f; unsigned int i; } v; v.f = f;
  unsigned int i = v.i;
  return (unsigned short)((i + 0x7FFFu + ((i >> 16) & 1u)) >> 16);
}
static __device__ __forceinline__ float sigf(float x) { return 1.f / (1.f + __expf(-x)); }

// ---------------- workspace layout (bytes) ----------------
// cnt    [0,1024)          barrier lines (16 x 64B) + cnt[255] = watchdog flag
// scan   [4096,102400)     cvec/coef/inv2 (3 x 8192 fp32)
// pe     [102400,153600)   100x128 fp32
// h1     [153600,284672)   2 slots x 32x1024 bf16
// h2     [284672,415744)
// cst    [415744,677888)   c1,c2 save
// melpre @ 720896          (4,096,000)
// wbf    @ 4,849,664       (10,485,760)  Wih1 bf16 [4096][1280]
// wimg   @ 15,728,640      (25,165,824)  per-WG recurrent B-frag images
// inp1c  @ 41,943,040      ((TC+2) x 81920)

// ---------------- init ----------------
__global__ void k_init(unsigned int* hzero, unsigned int* cnt, float* pe) {
  int idx = blockIdx.x * 256 + threadIdx.x;
  if (idx < 256) cnt[idx] = 0u;
  if (idx < 65536) hzero[idx] = 0u;                     // h1+h2 both slots
  if (idx < 6400) {
    int p = idx >> 6, i = idx & 63;
    float freq = __expf(-(float)(2 * i) * 0.0719557842162201f); // ln(10000)/128
    float a = (float)p * freq;
    pe[p * 128 + 2 * i]     = sinf(a);
    pe[p * 128 + 2 * i + 1] = cosf(a);
  }
}

// ---------------- prenet -> inp1c[:, 0:256] ----------------
__global__ __launch_bounds__(256) void k_prenet(const float* __restrict__ din,
                                                const float* __restrict__ u1,
                                                const float* __restrict__ u2,
                                                const float* __restrict__ Wp1,
                                                const float* __restrict__ Wp2,
                                                unsigned short* inp1c, int t0, int tbeg) {
  __shared__ float dec[2560];
  __shared__ float X1[8192];
  int t = tbeg + blockIdx.x, tid = threadIdx.x;
  int tt = t - t0;
  for (int i = tid; i < 2560; i += 256) {
    int b = i / 80, f = i % 80;
    dec[i] = (t == 0) ? 0.f : din[((size_t)b * 80 + f) * 800 + (t - 1)];
  }
  __syncthreads();
  int n = tid;
  for (int b = 0; b < 32; ++b) {
    float s = 0.f;
    const float* w = Wp1 + n * 80;
    const float* d = dec + b * 80;
#pragma unroll 8
    for (int f = 0; f < 80; ++f) s += d[f] * w[f];
    s = fmaxf(s, 0.f);
    float m = (u1[((size_t)t * 32 + b) * 256 + n] >= 0.5f) ? 2.f : 0.f;
    X1[b * 256 + n] = s * m;
  }
  __syncthreads();
  for (int b = 0; b < 32; ++b) {
    float s = 0.f;
    const float* w = Wp2 + n * 256;
    const float* x = X1 + b * 256;
#pragma unroll 8
    for (int kk = 0; kk < 256; ++kk) s += x[kk] * w[kk];
    s = fmaxf(s, 0.f);
    float m = (u2[((size_t)t * 32 + b) * 256 + n] >= 0.5f) ? 2.f : 0.f;
    inp1c[((size_t)tt * 32 + b) * 1280 + n] = f2b(s * m);
  }
}

// ---------------- attention precompute ----------------
__global__ __launch_bounds__(256) void k_attn_prep(const float* __restrict__ dur,
                                                   const float* __restrict__ range,
                                                   float* cvec, float* coef, float* inv2) {
  __shared__ float s[256];
  int b = blockIdx.x, e = threadIdx.x;
  float d = dur[b * 256 + e];
  s[e] = d;
  __syncthreads();
  for (int off = 1; off < 256; off <<= 1) {
    float v = (e >= off) ? s[e - off] : 0.f;
    __syncthreads();
    s[e] = s[e] + v;
    __syncthreads();
  }
  float c = s[e] - 0.5f * d;
  float sg = range[b * 256 + e] + 1e-5f;
  cvec[b * 256 + e] = c;
  coef[b * 256 + e] = rsqrtf(6.283185307179586f * sg * sg);
  inv2[b * 256 + e] = 1.f / (2.f * sg * sg);
}

// ---------------- alignments output (fp32) ----------------
__global__ __launch_bounds__(256) void k_attn(const float* __restrict__ cvec,
                                              const float* __restrict__ coef,
                                              const float* __restrict__ inv2,
                                              float* out_align) {
  __shared__ float red[4];
  int t = blockIdx.x, b = blockIdx.y, e = threadIdx.x;
  float dt = (float)t - cvec[b * 256 + e];
  float p = coef[b * 256 + e] * __expf(-dt * dt * inv2[b * 256 + e]) + 1e-5f;
  float s = p;
#pragma unroll
  for (int o = 1; o < 64; o <<= 1) s += __shfl_xor(s, o);
  if ((e & 63) == 0) red[e >> 6] = s;
  __syncthreads();
  float tot = red[0] + red[1] + red[2] + red[3];
  out_align[((size_t)b * 800 + t) * 256 + e] = p / tot;
}

// ---------------- context -> inp1c[:,256:1152] ----------------
__global__ __launch_bounds__(256) void k_ctx(const float* __restrict__ cvec,
                                             const float* __restrict__ coef,
                                             const float* __restrict__ inv2,
                                             const float* __restrict__ mem,
                                             unsigned short* inp1c,
                                             int t0, int tbeg, int tend) {
  __shared__ float wl[4096];
  __shared__ float rinv[16];
  int b = blockIdx.y, tB = tbeg + blockIdx.x * 16, tid = threadIdx.x;
  int nt = tend - tB; if (nt > 16) nt = 16;
  float cv = cvec[b * 256 + tid], co = coef[b * 256 + tid], iv = inv2[b * 256 + tid];
  for (int s = 0; s < nt; ++s) {
    float d = (float)(tB + s) - cv;
    wl[s * 256 + tid] = co * __expf(-d * d * iv) + 1e-5f;
  }
  for (int s = nt; s < 16; ++s) wl[s * 256 + tid] = 0.f;
  __syncthreads();
  int wv = tid >> 6, ln = tid & 63;
  for (int s = wv; s < nt; s += 4) {
    float x = wl[s * 256 + ln] + wl[s * 256 + 64 + ln] + wl[s * 256 + 128 + ln] + wl[s * 256 + 192 + ln];
#pragma unroll
    for (int o = 1; o < 64; o <<= 1) x += __shfl_xor(x, o);
    if (ln == 0) rinv[s] = 1.f / x;
  }
  __syncthreads();
  for (int s = 0; s < nt; ++s) wl[s * 256 + tid] *= rinv[s];
  __syncthreads();
  float acc[16][4];
#pragma unroll
  for (int s = 0; s < 16; ++s) { acc[s][0] = 0.f; acc[s][1] = 0.f; acc[s][2] = 0.f; acc[s][3] = 0.f; }
  for (int e = 0; e < 256; ++e) {
    const float* mrow = mem + ((size_t)b * 256 + e) * 896;
    float m0 = mrow[tid], m1 = mrow[tid + 256], m2 = mrow[tid + 512];
    float m3 = (tid < 128) ? mrow[tid + 768] : 0.f;
#pragma unroll
    for (int s = 0; s < 16; ++s) {
      float w = wl[s * 256 + e];
      acc[s][0] += w * m0; acc[s][1] += w * m1; acc[s][2] += w * m2; acc[s][3] += w * m3;
    }
  }
  for (int s = 0; s < nt; ++s) {
    size_t base = ((size_t)(tB - t0 + s) * 32 + b) * 1280 + 256;
    inp1c[base + tid]       = f2b(acc[s][0]);
    inp1c[base + tid + 256] = f2b(acc[s][1]);
    inp1c[base + tid + 512] = f2b(acc[s][2]);
    if (tid < 128) inp1c[base + tid + 768] = f2b(acc[s][3]);
  }
}

// ---------------- PE gather -> inp1c[:,1152:1280] ----------------
__global__ void k_pegather(const int* __restrict__ dfi, const float* __restrict__ pe,
                           unsigned short* inp1c, int t0, int tbeg, int R) {
  int idx = blockIdx.x * 256 + threadIdx.x;
  if (idx >= R * 4096) return;
  int d = idx & 127, r = idx >> 7;
  int b = r & 31, ti = r >> 5;
  int t = tbeg + ti;
  int pos = dfi[b * 800 + t];
  inp1c[((size_t)(t - t0) * 32 + b) * 1280 + 1152 + d] = f2b(pe[pos * 128 + d]);
}

// ---------------- Wih1 fp32 -> bf16 (round-nearest), [4096][1280] ----------------
__global__ void k_repackW(const float* __restrict__ Wih1, unsigned short* wbf) {
  int idx = blockIdx.x * 256 + threadIdx.x;
  if (idx >= 1310720) return;
  float4 f = *(const float4*)(Wih1 + (size_t)idx * 4);
  union { unsigned short us[4]; unsigned long long q; } o;
  o.us[0] = f2b(f.x); o.us[1] = f2b(f.y); o.us[2] = f2b(f.z); o.us[3] = f2b(f.w);
  *(unsigned long long*)(wbf + (size_t)idx * 4) = o.q;
}

// ---------------- per-WG recurrent B-frag images -> global wimg ----------------
// wimg[wg][gi][ks][lane][e], gi: 0=Whh1 1=Wih2 2=Whh2 (exactly the old in-LDS layout)
__global__ void k_repackImg(const float* __restrict__ Whh1, const float* __restrict__ Wih2,
                            const float* __restrict__ Whh2, unsigned short* wimg) {
  size_t idx = (size_t)blockIdx.x * 256 + threadIdx.x;
  if (idx >= 12582912ull) return;
  int wg = (int)(idx / 49152);
  int rem = (int)(idx % 49152);
  int gi = rem / 16384;
  int r2 = rem & 16383;
  int ks = r2 >> 9;
  int l  = (r2 >> 3) & 63;
  int e  = r2 & 7;
  int nn = l & 15, kq = l >> 4;
  int row = (nn >> 2) * 1024 + wg * 4 + (nn & 3);
  int kk = ks * 32 + kq * 8 + e;
  const float* W = (gi == 0) ? Whh1 : (gi == 1) ? Wih2 : Whh2;
  wimg[idx] = f2b(W[(size_t)row * 1024 + kk]);
}

// ---------------- melpre[t][b][c] = ctx_pe . Wproj[c,1024:2048] + bproj[c] ----------------
__global__ __launch_bounds__(256) void k_melpre(const unsigned short* __restrict__ inp1c,
                                                const float* __restrict__ Wproj,
                                                const float* __restrict__ bproj,
                                                unsigned short* melpre, int t0, int tbeg) {
  extern __shared__ unsigned short ctx[];  // 32*1024 bf16
  int t = tbeg + blockIdx.x, tid = threadIdx.x;
  int tt = t - t0;
  for (int i = tid; i < 32768; i += 256)
    ctx[i] = inp1c[((size_t)tt * 32 + (i >> 10)) * 1280 + 256 + (i & 1023)];
  __syncthreads();
  if (tid < 240) {
    int c = tid % 80, bs = tid / 80;
    const float* w = Wproj + (size_t)c * 2048 + 1024;
    for (int b = bs; b < 32; b += 3) {
      float s = bproj[c];
      const unsigned short* x = ctx + b * 1024;
#pragma unroll 8
      for (int kk = 0; kk < 1024; ++kk) s += b2f(x[kk]) * w[kk];
      melpre[((size_t)t * 32 + b) * 80 + c] = f2b(s);
    }
  }
}

// ---------------- persistent cooperative decoder ----------------
struct DecArgs {
  const unsigned short* inp1c;
  const unsigned short* wbf;
  const unsigned short* wimg;
  const float* bih1; const float* bhh1; const float* bih2; const float* bhh2;
  const float* Wproj; const float* bproj;
  const unsigned short* melpre;
  unsigned short* h1; unsigned short* h2; float* cst;
  unsigned int* cnt; float* out_mel;
  int k0, k1;
};

// LDS offsets (dynamic smem, 139264 requested):
//   h1s @ 0      (65536)  staged h1[k-1], XOR-swizzled
//   h2s @ 65536  (65536)  staged h2[k-2]
//   g1  @ 131072 (2176) g2a @ 133248 g2b @ 135424
//   c1  @ 137600 (512)  c2 @ 138112 (512)
//   bias1 @ 138624 (64) bias2 @ 138688 (64)
__global__ __launch_bounds__(512, 1) void k_decode(DecArgs A) {
  extern __shared__ char smem[];
  float (*g1)[17]  = (float(*)[17])(smem + 131072);
  float (*g2a)[17] = (float(*)[17])(smem + 133248);
  float (*g2b)[17] = (float(*)[17])(smem + 135424);
  float (*c1)[4]   = (float(*)[4])(smem + 137600);
  float (*c2)[4]   = (float(*)[4])(smem + 138112);
  float* bias1     = (float*)(smem + 138624);
  float* bias2     = (float*)(smem + 138688);

  int wg = blockIdx.x, tid = threadIdx.x;
  int wid = tid >> 6, lane = tid & 63;
  int k0 = A.k0, k1 = A.k1;
  const unsigned short* wimg_wg = A.wimg + (size_t)wg * 49152;

  if (tid < 16) {
    int row = (tid >> 2) * 1024 + wg * 4 + (tid & 3);
    bias1[tid] = A.bih1[row] + A.bhh1[row];
    bias2[tid] = A.bih2[row] + A.bhh2[row];
  }
  if (tid < 128) {
    int b = tid >> 2, jj = tid & 3;
    c1[b][jj] = (k0 == 0) ? 0.f : A.cst[((size_t)wg * 32 + b) * 4 + jj];
  } else if (tid < 256) {
    int b = (tid - 128) >> 2, jj = tid & 3;
    c2[b][jj] = (k0 == 0) ? 0.f : A.cst[32768 + ((size_t)wg * 32 + b) * 4 + jj];
  }
  __syncthreads();

  long totspin = 0;
  for (int k = k0; k < k1; ++k) {
    bool do1 = (k < 800);
    bool do2 = (k >= 1 && k <= 800);

    // ---- cooperative stage: h1[k-1] + h2[k-2] -> LDS (XOR-swizzled), ONE read of each ----
    {
      const unsigned long long* s1 = (const unsigned long long*)(A.h1 + ((k - 1) & 1) * 32768);
      const unsigned long long* s2 = (const unsigned long long*)(A.h2 + (k & 1) * 32768);
#pragma unroll
      for (int j = 0; j < 8; ++j) {
        int m = j * 512 + tid;                      // 16B-pair index 0..4095
        unsigned long long a0 = __hip_atomic_load(s1 + 2 * m,     __ATOMIC_RELAXED, AGENT);
        unsigned long long a1 = __hip_atomic_load(s1 + 2 * m + 1, __ATOMIC_RELAXED, AGENT);
        unsigned long long b0 = __hip_atomic_load(s2 + 2 * m,     __ATOMIC_RELAXED, AGENT);
        unsigned long long b1 = __hip_atomic_load(s2 + 2 * m + 1, __ATOMIC_RELAXED, AGENT);
        int sw = (m * 16) ^ (((m >> 7) & 7) << 4);
        ulonglong2 va; va.x = a0; va.y = a1;
        ulonglong2 vb; vb.x = b0; vb.y = b1;
        *(ulonglong2*)(smem + sw) = va;
        *(ulonglong2*)(smem + 65536 + sw) = vb;
      }
    }
    __syncthreads();

    if (wid < 2) {
      if (do1) {
        int nn = lane & 15, kq = lane >> 4;
        int brow = wid * 16 + nn;
        int row = (nn >> 2) * 1024 + wg * 4 + (nn & 3);
        f32x4 a0 = {0.f,0.f,0.f,0.f}, a1 = {0.f,0.f,0.f,0.f};
        // x-GEMM (global, L2-resident)
        size_t tt = (size_t)(k - k0 + 2);
        const unsigned short* arow = A.inp1c + (tt * 32 + brow) * 1280 + kq * 8;
        const unsigned short* wrow = A.wbf + (size_t)row * 1280 + kq * 8;
#pragma unroll 4
        for (int ks = 0; ks < 40; ks += 2) {
          bfrag8 aA = *(const bfrag8*)(arow + ks * 32);
          bfrag8 aB = *(const bfrag8*)(arow + ks * 32 + 32);
          bfrag8 b0 = *(const bfrag8*)(wrow + ks * 32);
          bfrag8 b1 = *(const bfrag8*)(wrow + ks * 32 + 32);
          a0 = __builtin_amdgcn_mfma_f32_16x16x32_bf16(aA, b0, a0, 0, 0, 0);
          a1 = __builtin_amdgcn_mfma_f32_16x16x32_bf16(aB, b1, a1, 0, 0, 0);
        }
        // h1 from LDS, B-frags from global wimg
        const bfrag8* bp = (const bfrag8*)wimg_wg + lane;
        int sbase = brow * 2048 + kq * 16;
        int sxor = (brow & 7) << 4;
#pragma unroll
        for (int ks = 0; ks < 32; ks += 2) {
          ulonglong2 v0 = *(const ulonglong2*)(smem + ((sbase + ks * 64) ^ sxor));
          ulonglong2 v1 = *(const ulonglong2*)(smem + ((sbase + (ks + 1) * 64) ^ sxor));
          union { unsigned long long q[2]; bfrag8 v; } aa, ab;
          aa.q[0] = v0.x; aa.q[1] = v0.y;
          ab.q[0] = v1.x; ab.q[1] = v1.y;
          a0 = __builtin_amdgcn_mfma_f32_16x16x32_bf16(aa.v, bp[ks * 64], a0, 0, 0, 0);
          a1 = __builtin_amdgcn_mfma_f32_16x16x32_bf16(ab.v, bp[(ks + 1) * 64], a1, 0, 0, 0);
        }
        f32x4 acc = a0 + a1;
#pragma unroll
        for (int q = 0; q < 4; ++q) g1[wid * 16 + kq * 4 + q][nn] = acc[q];
      }
    } else if (wid < 6) {
      if (do2) {
        int mt, imgbase, hoff;
        if (wid < 4) { mt = wid - 2; imgbase = 2048; hoff = 0; }       // h1 staged
        else         { mt = wid - 4; imgbase = 4096; hoff = 65536; }   // h2 staged
        int nn = lane & 15, kq = lane >> 4;
        int brow = mt * 16 + nn;
        f32x4 a0 = {0.f,0.f,0.f,0.f}, a1 = {0.f,0.f,0.f,0.f};
        const bfrag8* bp = (const bfrag8*)wimg_wg + imgbase + lane;
        int sbase = hoff + brow * 2048 + kq * 16;
        int sxor = (brow & 7) << 4;
#pragma unroll
        for (int ks = 0; ks < 32; ks += 2) {
          ulonglong2 v0 = *(const ulonglong2*)(smem + ((sbase + ks * 64) ^ sxor));
          ulonglong2 v1 = *(const ulonglong2*)(smem + ((sbase + (ks + 1) * 64) ^ sxor));
          union { unsigned long long q[2]; bfrag8 v; } aa, ab;
          aa.q[0] = v0.x; aa.q[1] = v0.y;
          ab.q[0] = v1.x; ab.q[1] = v1.y;
          a0 = __builtin_amdgcn_mfma_f32_16x16x32_bf16(aa.v, bp[ks * 64], a0, 0, 0, 0);
          a1 = __builtin_amdgcn_mfma_f32_16x16x32_bf16(ab.v, bp[(ks + 1) * 64], a1, 0, 0, 0);
        }
        f32x4 acc = a0 + a1;
        float (*gb)[17] = (wid < 4) ? g2a : g2b;
#pragma unroll
        for (int q = 0; q < 4; ++q) gb[mt * 16 + kq * 4 + q][nn] = acc[q];
      }
    } else {
      if (k >= 2 && wg < 80) {
        int t = k - 2;
        int L = (wid - 6) * 64 + lane;
        int b = L >> 2, q = L & 3;
        const float* wp = A.Wproj + (size_t)wg * 2048 + q * 256;
        float s0 = 0.f, s1v = 0.f;
        int sbase = 65536 + b * 2048 + q * 512;
        int sxor = (b & 7) << 4;
#pragma unroll 8
        for (int ii = 0; ii < 32; ++ii) {
          ulonglong2 v = *(const ulonglong2*)(smem + ((sbase + ii * 16) ^ sxor));
          union { unsigned long long q; unsigned short u[4]; } a_, b2_;
          a_.q = v.x; b2_.q = v.y;
          const float* w0 = wp + ii * 8;
          s0  += b2f(a_.u[0])*w0[0] + b2f(a_.u[1])*w0[1] + b2f(a_.u[2])*w0[2] + b2f(a_.u[3])*w0[3];
          s1v += b2f(b2_.u[0])*w0[4] + b2f(b2_.u[1])*w0[5] + b2f(b2_.u[2])*w0[6] + b2f(b2_.u[3])*w0[7];
        }
        float s = s0 + s1v;
        s += __shfl_xor(s, 1);
        s += __shfl_xor(s, 2);
        if (q == 0) {
          float add = b2f(A.melpre[((size_t)t * 32 + b) * 80 + wg]);
          A.out_mel[(size_t)b * 64000 + (size_t)wg * 800 + t] = s + add;   // fp32 output
        }
      }
    }
    __syncthreads();
    if (tid < 128) {
      if (do1) {
        int b = tid >> 2, jj = tid & 3;
        float gi = g1[b][jj]      + bias1[jj];
        float gf = g1[b][4 + jj]  + bias1[4 + jj];
        float gg = g1[b][8 + jj]  + bias1[8 + jj];
        float go = g1[b][12 + jj] + bias1[12 + jj];
        float c = c1[b][jj];
        float cn = sigf(gf) * c + sigf(gi) * tanhf(gg);
        c1[b][jj] = cn;
        float hn = sigf(go) * tanhf(cn);
        float ho = __shfl_xor(hn, 1);
        if ((jj & 1) == 0) {
          unsigned int pk = (unsigned int)f2b(hn) | ((unsigned int)f2b(ho) << 16);
          __hip_atomic_store((unsigned int*)(A.h1 + (k & 1) * 32768 + b * 1024 + wg * 4 + jj), pk,
                             __ATOMIC_RELAXED, AGENT);
        }
      }
    } else if (tid < 256) {
      if (do2) {
        int b = (tid - 128) >> 2, jj = tid & 3;
        float gi = g2a[b][jj]      + g2b[b][jj]      + bias2[jj];
        float gf = g2a[b][4 + jj]  + g2b[b][4 + jj]  + bias2[4 + jj];
        float gg = g2a[b][8 + jj]  + g2b[b][8 + jj]  + bias2[8 + jj];
        float go = g2a[b][12 + jj] + g2b[b][12 + jj] + bias2[12 + jj];
        float c = c2[b][jj];
        float cn = sigf(gf) * c + sigf(gi) * tanhf(gg);
        c2[b][jj] = cn;
        float hn = sigf(go) * tanhf(cn);
        float ho = __shfl_xor(hn, 1);
        if ((jj & 1) == 0) {
          unsigned int pk = (unsigned int)f2b(hn) | ((unsigned int)f2b(ho) << 16);
          __hip_atomic_store((unsigned int*)(A.h2 + ((k - 1) & 1) * 32768 + b * 1024 + wg * 4 + jj), pk,
                             __ATOMIC_RELAXED, AGENT);
        }
      }
    }
    __syncthreads();   // drains vmcnt(0): all h-stores of this WG committed before arrive
    if (tid == 0) {
      asm volatile("s_waitcnt vmcnt(0)" ::: "memory");
      __hip_atomic_fetch_add(A.cnt + (wg & 15) * 16, 1u, __ATOMIC_RELAXED, AGENT);
    }
    if (tid < 16 && totspin >= 0) {
      unsigned int tgt = (unsigned int)(k + 1) * 16u;
      while (__hip_atomic_load(A.cnt + tid * 16, __ATOMIC_RELAXED, AGENT) < tgt) {
        __builtin_amdgcn_s_sleep(2);
        if (++totspin > (1l << 25)) {          // watchdog: record + free-run, never hang
          totspin = -1;
          __hip_atomic_fetch_add(A.cnt + 255, 1u, __ATOMIC_RELAXED, AGENT);
          break;
        }
      }
    }
    __syncthreads();
  }
  if (tid < 128) {
    int b = tid >> 2, jj = tid & 3;
    A.cst[((size_t)wg * 32 + b) * 4 + jj] = c1[b][jj];
  } else if (tid < 256) {
    int b = (tid - 128) >> 2, jj = tid & 3;
    A.cst[32768 + ((size_t)wg * 32 + b) * 4 + jj] = c2[b][jj];
  }
}

// ---------------- diagnostics (fp32) ----------------
__global__ void k_diag(float* out_mel, float wsmb) {
  out_mel[0] = 1000.f + wsmb;                 // ~1000+MB => ws too small
}
__global__ void k_verify(const unsigned int* cnt, float* out_mel) {
  unsigned int tot = 0;
  for (int i = 0; i < 16; ++i) tot += cnt[i * 16];
  unsigned int wd = cnt[255];
  if (wd)
    out_mel[0] = 5000.f + (float)(wd > 900u ? 900u : wd);      // ~5000+ => barrier desync
  else if (tot != 802u * 256u)
    out_mel[0] = 3000.f + (float)tot * (1.f / 256.f);          // ~3000+ => decode stalled
}

extern "C" void kernel_launch(void* const* d_in, const int* in_sizes, int n_in,
                              void* d_out, int out_size, void* d_ws, size_t ws_size,
                              hipStream_t stream) {
  const float* memory = (const float*)d_in[0];
  const float* dur    = (const float*)d_in[1];
  const int*   dfi    = (const int*)d_in[2];
  const float* range  = (const float*)d_in[3];
  const float* din    = (const float*)d_in[4];
  const float* Wp1    = (const float*)d_in[6];
  const float* Wp2    = (const float*)d_in[7];
  const float* Wih1   = (const float*)d_in[8];
  const float* Whh1   = (const float*)d_in[9];
  const float* bih1   = (const float*)d_in[10];
  const float* bhh1   = (const float*)d_in[11];
  const float* Wih2   = (const float*)d_in[12];
  const float* Whh2   = (const float*)d_in[13];
  const float* bih2   = (const float*)d_in[14];
  const float* bhh2   = (const float*)d_in[15];
  const float* Wproj  = (const float*)d_in[16];
  const float* bproj  = (const float*)d_in[17];
  const float* u1     = (const float*)d_in[18];
  const float* u2     = (const float*)d_in[19];

  char* ws = (char*)d_ws;
  unsigned int* cnt   = (unsigned int*)ws;
  float* cvec         = (float*)(ws + 4096);
  float* coef         = cvec + 8192;
  float* inv2         = coef + 8192;
  float* pe           = (float*)(ws + 102400);
  unsigned short* h1  = (unsigned short*)(ws + 153600);
  unsigned short* h2  = h1 + 65536;
  float* cst          = (float*)(ws + 415744);
  unsigned short* melpre = (unsigned short*)(ws + 720896);
  unsigned short* wbf    = (unsigned short*)(ws + 4849664);
  unsigned short* wimg   = (unsigned short*)(ws + 15728640);
  unsigned short* inp1c  = (unsigned short*)(ws + 41943040ull);

  float* out_mel   = (float*)d_out;                         // fp32 outputs (reference dtype)
  float* out_align = out_mel + 2048000;

  const size_t BASE = 41943040ull;
  int TC;
  if      (ws_size >= BASE + 802ull * 81920ull) TC = 800;
  else if (ws_size >= BASE + 202ull * 81920ull) TC = 200;
  else if (ws_size >= BASE +  82ull * 81920ull) TC = 80;
  else if (ws_size >= BASE +  42ull * 81920ull) TC = 40;
  else {
    k_diag<<<1, 1, 0, stream>>>(out_mel, (float)(ws_size >> 20));
    return;
  }

  hipFuncSetAttribute((const void*)k_decode, hipFuncAttributeMaxDynamicSharedMemorySize, 147456);
  hipFuncSetAttribute((const void*)k_melpre, hipFuncAttributeMaxDynamicSharedMemorySize, 98304);

  k_init<<<256, 256, 0, stream>>>((unsigned int*)(ws + 153600), cnt, pe);
  k_attn_prep<<<32, 256, 0, stream>>>(dur, range, cvec, coef, inv2);
  k_attn<<<dim3(800, 32), 256, 0, stream>>>(cvec, coef, inv2, out_align);
  k_repackW<<<5120, 256, 0, stream>>>(Wih1, wbf);
  k_repackImg<<<49152, 256, 0, stream>>>(Whh1, Wih2, Whh2, wimg);

  DecArgs da[20];
  int nch = (800 + TC - 1) / TC;
  for (int c = 0; c < nch; ++c) {
    int k0 = c * TC;
    int k1 = (c == nch - 1) ? 802 : (c + 1) * TC;
    int t0 = k0 - 2;
    int tbeg = t0 < 0 ? 0 : t0;
    int tend = k1 < 800 ? k1 : 800;
    int R = tend - tbeg;
    k_prenet<<<R, 256, 0, stream>>>(din, u1, u2, Wp1, Wp2, inp1c, t0, tbeg);
    k_ctx<<<dim3((R + 15) / 16, 32), 256, 0, stream>>>(cvec, coef, inv2, memory, inp1c, t0, tbeg, tend);
    k_pegather<<<(R * 4096 + 255) / 256, 256, 0, stream>>>(dfi, pe, inp1c, t0, tbeg, R);
    k_melpre<<<R, 256, 65536, stream>>>(inp1c, Wproj, bproj, melpre, t0, tbeg);

    da[c] = DecArgs{ inp1c, wbf, wimg, bih1, bhh1, bih2, bhh2,
                     Wproj, bproj, melpre, h1, h2, cst, cnt, out_mel, k0, k1 };
    void* kp[1] = { &da[c] };
    hipLaunchCooperativeKernel((const void*)k_decode, dim3(256), dim3(512), kp, 139264, stream);
  }
  k_verify<<<1, 1, 0, stream>>>(cnt, out_mel);
}

// Round 10
// 22173.979 us; speedup vs baseline: 1.3123x; 1.0076x over previous
//
#include <hip/hip_runtime.h>
#include <hip/hip_bf16.h>
#include <math.h>

typedef __attribute__((ext_vector_type(8))) short bfrag8;   // 8 x bf16
typedef __attribute__((ext_vector_type(4))) float f32x4;    // MFMA accumulator
#define AGENT __HIP_MEMORY_SCOPE_AGENT

static __device__ __forceinline__ float b2f(unsigned short u) {
  union { unsigned int i; float f; } v; v.i = ((unsigned int)u) << 16; return v.f;
}
static __device__ __forceinline__ unsigned short f2b(float f) {
  union { float f; unsigned int i; } v; v.f = f;
  unsigned int i = v.i;
  return (unsigned short)((i + 0x7FFFu + ((i >> 16) & 1u)) >> 16);
}
static __device__ __forceinline__ float sigf(float x) { return 1.f / (1.f + __expf(-x)); }

// ---------------- workspace layout (bytes) ----------------
// cnt    [0,1024)          barrier lines (16 x 64B) + cnt[255] = watchdog flag
// scan   [4096,102400)     cvec/coef/inv2 (3 x 8192 fp32)
// pe     [102400,153600)   100x128 fp32
// h1     [153600,284672)   2 slots x 32x1024 bf16
// h2     [284672,415744)
// cst    [415744,677888)   c1,c2 save
// melpre @ 720896          (4,096,000)
// wbf    @ 4,849,664       (10,485,760)  Wih1 bf16 [4096][1280]
// wimg   @ 15,728,640      (25,165,824)  per-WG recurrent B-frag images
// inp1c  @ 41,943,040      ((TC+2) x 81920)

// ---------------- init ----------------
__global__ void k_init(unsigned int* hzero, unsigned int* cnt, float* pe) {
  int idx = blockIdx.x * 256 + threadIdx.x;
  if (idx < 256) cnt[idx] = 0u;
  if (idx < 65536) hzero[idx] = 0u;                     // h1+h2 both slots
  if (idx < 6400) {
    int p = idx >> 6, i = idx & 63;
    float freq = __expf(-(float)(2 * i) * 0.0719557842162201f); // ln(10000)/128
    float a = (float)p * freq;
    pe[p * 128 + 2 * i]     = sinf(a);
    pe[p * 128 + 2 * i + 1] = cosf(a);
  }
}

// ---------------- prenet -> inp1c[:, 0:256] ----------------
__global__ __launch_bounds__(256) void k_prenet(const float* __restrict__ din,
                                                const float* __restrict__ u1,
                                                const float* __restrict__ u2,
                                                const float* __restrict__ Wp1,
                                                const float* __restrict__ Wp2,
                                                unsigned short* inp1c, int t0, int tbeg) {
  __shared__ float dec[2560];
  __shared__ float X1[8192];
  int t = tbeg + blockIdx.x, tid = threadIdx.x;
  int tt = t - t0;
  for (int i = tid; i < 2560; i += 256) {
    int b = i / 80, f = i % 80;
    dec[i] = (t == 0) ? 0.f : din[((size_t)b * 80 + f) * 800 + (t - 1)];
  }
  __syncthreads();
  int n = tid;
  for (int b = 0; b < 32; ++b) {
    float s = 0.f;
    const float* w = Wp1 + n * 80;
    const float* d = dec + b * 80;
#pragma unroll 8
    for (int f = 0; f < 80; ++f) s += d[f] * w[f];
    s = fmaxf(s, 0.f);
    float m = (u1[((size_t)t * 32 + b) * 256 + n] >= 0.5f) ? 2.f : 0.f;
    X1[b * 256 + n] = s * m;
  }
  __syncthreads();
  for (int b = 0; b < 32; ++b) {
    float s = 0.f;
    const float* w = Wp2 + n * 256;
    const float* x = X1 + b * 256;
#pragma unroll 8
    for (int kk = 0; kk < 256; ++kk) s += x[kk] * w[kk];
    s = fmaxf(s, 0.f);
    float m = (u2[((size_t)t * 32 + b) * 256 + n] >= 0.5f) ? 2.f : 0.f;
    inp1c[((size_t)tt * 32 + b) * 1280 + n] = f2b(s * m);
  }
}

// ---------------- attention precompute ----------------
__global__ __launch_bounds__(256) void k_attn_prep(const float* __restrict__ dur,
                                                   const float* __restrict__ range,
                                                   float* cvec, float* coef, float* inv2) {
  __shared__ float s[256];
  int b = blockIdx.x, e = threadIdx.x;
  float d = dur[b * 256 + e];
  s[e] = d;
  __syncthreads();
  for (int off = 1; off < 256; off <<= 1) {
    float v = (e >= off) ? s[e - off] : 0.f;
    __syncthreads();
    s[e] = s[e] + v;
    __syncthreads();
  }
  float c = s[e] - 0.5f * d;
  float sg = range[b * 256 + e] + 1e-5f;
  cvec[b * 256 + e] = c;
  coef[b * 256 + e] = rsqrtf(6.283185307179586f * sg * sg);
  inv2[b * 256 + e] = 1.f / (2.f * sg * sg);
}

// ---------------- alignments output (fp32) ----------------
__global__ __launch_bounds__(256) void k_attn(const float* __restrict__ cvec,
                                              const float* __restrict__ coef,
                                              const float* __restrict__ inv2,
                                              float* out_align) {
  __shared__ float red[4];
  int t = blockIdx.x, b = blockIdx.y, e = threadIdx.x;
  float dt = (float)t - cvec[b * 256 + e];
  float p = coef[b * 256 + e] * __expf(-dt * dt * inv2[b * 256 + e]) + 1e-5f;
  float s = p;
#pragma unroll
  for (int o = 1; o < 64; o <<= 1) s += __shfl_xor(s, o);
  if ((e & 63) == 0) red[e >> 6] = s;
  __syncthreads();
  float tot = red[0] + red[1] + red[2] + red[3];
  out_align[((size_t)b * 800 + t) * 256 + e] = p / tot;
}

// ---------------- context -> inp1c[:,256:1152] ----------------
__global__ __launch_bounds__(256) void k_ctx(const float* __restrict__ cvec,
                                             const float* __restrict__ coef,
                                             const float* __restrict__ inv2,
                                             const float* __restrict__ mem,
                                             unsigned short* inp1c,
                                             int t0, int tbeg, int tend) {
  __shared__ float wl[4096];
  __shared__ float rinv[16];
  int b = blockIdx.y, tB = tbeg + blockIdx.x * 16, tid = threadIdx.x;
  int nt = tend - tB; if (nt > 16) nt = 16;
  float cv = cvec[b * 256 + tid], co = coef[b * 256 + tid], iv = inv2[b * 256 + tid];
  for (int s = 0; s < nt; ++s) {
    float d = (float)(tB + s) - cv;
    wl[s * 256 + tid] = co * __expf(-d * d * iv) + 1e-5f;
  }
  for (int s = nt; s < 16; ++s) wl[s * 256 + tid] = 0.f;
  __syncthreads();
  int wv = tid >> 6, ln = tid & 63;
  for (int s = wv; s < nt; s += 4) {
    float x = wl[s * 256 + ln] + wl[s * 256 + 64 + ln] + wl[s * 256 + 128 + ln] + wl[s * 256 + 192 + ln];
#pragma unroll
    for (int o = 1; o < 64; o <<= 1) x += __shfl_xor(x, o);
    if (ln == 0) rinv[s] = 1.f / x;
  }
  __syncthreads();
  for (int s = 0; s < nt; ++s) wl[s * 256 + tid] *= rinv[s];
  __syncthreads();
  float acc[16][4];
#pragma unroll
  for (int s = 0; s < 16; ++s) { acc[s][0] = 0.f; acc[s][1] = 0.f; acc[s][2] = 0.f; acc[s][3] = 0.f; }
  for (int e = 0; e < 256; ++e) {
    const float* mrow = mem + ((size_t)b * 256 + e) * 896;
    float m0 = mrow[tid], m1 = mrow[tid + 256], m2 = mrow[tid + 512];
    float m3 = (tid < 128) ? mrow[tid + 768] : 0.f;
#pragma unroll
    for (int s = 0; s < 16; ++s) {
      float w = wl[s * 256 + e];
      acc[s][0] += w * m0; acc[s][1] += w * m1; acc[s][2] += w * m2; acc[s][3] += w * m3;
    }
  }
  for (int s = 0; s < nt; ++s) {
    size_t base = ((size_t)(tB - t0 + s) * 32 + b) * 1280 + 256;
    inp1c[base + tid]       = f2b(acc[s][0]);
    inp1c[base + tid + 256] = f2b(acc[s][1]);
    inp1c[base + tid + 512] = f2b(acc[s][2]);
    if (tid < 128) inp1c[base + tid + 768] = f2b(acc[s][3]);
  }
}

// ---------------- PE gather -> inp1c[:,1152:1280] ----------------
__global__ void k_pegather(const int* __restrict__ dfi, const float* __restrict__ pe,
                           unsigned short* inp1c, int t0, int tbeg, int R) {
  int idx = blockIdx.x * 256 + threadIdx.x;
  if (idx >= R * 4096) return;
  int d = idx & 127, r = idx >> 7;
  int b = r & 31, ti = r >> 5;
  int t = tbeg + ti;
  int pos = dfi[b * 800 + t];
  inp1c[((size_t)(t - t0) * 32 + b) * 1280 + 1152 + d] = f2b(pe[pos * 128 + d]);
}

// ---------------- Wih1 fp32 -> bf16 (round-nearest), [4096][1280] ----------------
__global__ void k_repackW(const float* __restrict__ Wih1, unsigned short* wbf) {
  int idx = blockIdx.x * 256 + threadIdx.x;
  if (idx >= 1310720) return;
  float4 f = *(const float4*)(Wih1 + (size_t)idx * 4);
  union { unsigned short us[4]; unsigned long long q; } o;
  o.us[0] = f2b(f.x); o.us[1] = f2b(f.y); o.us[2] = f2b(f.z); o.us[3] = f2b(f.w);
  *(unsigned long long*)(wbf + (size_t)idx * 4) = o.q;
}

// ---------------- per-WG recurrent B-frag images -> global wimg ----------------
// wimg[wg][gi][ks][lane][e], gi: 0=Whh1 1=Wih2 2=Whh2
__global__ void k_repackImg(const float* __restrict__ Whh1, const float* __restrict__ Wih2,
                            const float* __restrict__ Whh2, unsigned short* wimg) {
  size_t idx = (size_t)blockIdx.x * 256 + threadIdx.x;
  if (idx >= 12582912ull) return;
  int wg = (int)(idx / 49152);
  int rem = (int)(idx % 49152);
  int gi = rem / 16384;
  int r2 = rem & 16383;
  int ks = r2 >> 9;
  int l  = (r2 >> 3) & 63;
  int e  = r2 & 7;
  int nn = l & 15, kq = l >> 4;
  int row = (nn >> 2) * 1024 + wg * 4 + (nn & 3);
  int kk = ks * 32 + kq * 8 + e;
  const float* W = (gi == 0) ? Whh1 : (gi == 1) ? Wih2 : Whh2;
  wimg[idx] = f2b(W[(size_t)row * 1024 + kk]);
}

// ---------------- melpre[t][b][c] = ctx_pe . Wproj[c,1024:2048] + bproj[c] ----------------
__global__ __launch_bounds__(256) void k_melpre(const unsigned short* __restrict__ inp1c,
                                                const float* __restrict__ Wproj,
                                                const float* __restrict__ bproj,
                                                unsigned short* melpre, int t0, int tbeg) {
  extern __shared__ unsigned short ctx[];  // 32*1024 bf16
  int t = tbeg + blockIdx.x, tid = threadIdx.x;
  int tt = t - t0;
  for (int i = tid; i < 32768; i += 256)
    ctx[i] = inp1c[((size_t)tt * 32 + (i >> 10)) * 1280 + 256 + (i & 1023)];
  __syncthreads();
  if (tid < 240) {
    int c = tid % 80, bs = tid / 80;
    const float* w = Wproj + (size_t)c * 2048 + 1024;
    for (int b = bs; b < 32; b += 3) {
      float s = bproj[c];
      const unsigned short* x = ctx + b * 1024;
#pragma unroll 8
      for (int kk = 0; kk < 1024; ++kk) s += b2f(x[kk]) * w[kk];
      melpre[((size_t)t * 32 + b) * 80 + c] = f2b(s);
    }
  }
}

// 8 coherent (L2-bypassing) 16B loads in flight, one drain.
#define COH_LOAD8(d0,d1,d2,d3,d4,d5,d6,d7, p0,p1,p2,p3,p4,p5,p6,p7)       \
  asm volatile(                                                            \
    "global_load_dwordx4 %0, %8, off sc0 sc1\n\t"                          \
    "global_load_dwordx4 %1, %9, off sc0 sc1\n\t"                          \
    "global_load_dwordx4 %2, %10, off sc0 sc1\n\t"                         \
    "global_load_dwordx4 %3, %11, off sc0 sc1\n\t"                         \
    "global_load_dwordx4 %4, %12, off sc0 sc1\n\t"                         \
    "global_load_dwordx4 %5, %13, off sc0 sc1\n\t"                         \
    "global_load_dwordx4 %6, %14, off sc0 sc1\n\t"                         \
    "global_load_dwordx4 %7, %15, off sc0 sc1\n\t"                         \
    "s_waitcnt vmcnt(0)"                                                   \
    : "=&v"(d0), "=&v"(d1), "=&v"(d2), "=&v"(d3),                          \
      "=&v"(d4), "=&v"(d5), "=&v"(d6), "=&v"(d7)                           \
    : "v"(p0), "v"(p1), "v"(p2), "v"(p3),                                  \
      "v"(p4), "v"(p5), "v"(p6), "v"(p7)                                   \
    : "memory")

// ---------------- persistent cooperative decoder ----------------
struct DecArgs {
  const unsigned short* inp1c;
  const unsigned short* wbf;
  const unsigned short* wimg;
  const float* bih1; const float* bhh1; const float* bih2; const float* bhh2;
  const float* Wproj; const float* bproj;
  const unsigned short* melpre;
  unsigned short* h1; unsigned short* h2; float* cst;
  unsigned int* cnt; float* out_mel;
  int k0, k1;
};

// LDS offsets (dynamic smem, 139264 requested):
//   h1s @ 0      (65536)  staged h1[k-1], XOR-swizzled
//   h2s @ 65536  (65536)  staged h2[k-2]
//   g1  @ 131072 (2176) g2a @ 133248 g2b @ 135424
//   c1  @ 137600 (512)  c2 @ 138112 (512)
//   bias1 @ 138624 (64) bias2 @ 138688 (64)
__global__ __launch_bounds__(512, 1) void k_decode(DecArgs A) {
  extern __shared__ char smem[];
  float (*g1)[17]  = (float(*)[17])(smem + 131072);
  float (*g2a)[17] = (float(*)[17])(smem + 133248);
  float (*g2b)[17] = (float(*)[17])(smem + 135424);
  float (*c1)[4]   = (float(*)[4])(smem + 137600);
  float (*c2)[4]   = (float(*)[4])(smem + 138112);
  float* bias1     = (float*)(smem + 138624);
  float* bias2     = (float*)(smem + 138688);

  int wg = blockIdx.x, tid = threadIdx.x;
  int wid = tid >> 6, lane = tid & 63;
  int k0 = A.k0, k1 = A.k1;
  const unsigned short* wimg_wg = A.wimg + (size_t)wg * 49152;

  if (tid < 16) {
    int row = (tid >> 2) * 1024 + wg * 4 + (tid & 3);
    bias1[tid] = A.bih1[row] + A.bhh1[row];
    bias2[tid] = A.bih2[row] + A.bhh2[row];
  }
  if (tid < 128) {
    int b = tid >> 2, jj = tid & 3;
    c1[b][jj] = (k0 == 0) ? 0.f : A.cst[((size_t)wg * 32 + b) * 4 + jj];
  } else if (tid < 256) {
    int b = (tid - 128) >> 2, jj = tid & 3;
    c2[b][jj] = (k0 == 0) ? 0.f : A.cst[32768 + ((size_t)wg * 32 + b) * 4 + jj];
  }
  __syncthreads();

  long totspin = 0;
  for (int k = k0; k < k1; ++k) {
    bool do1 = (k < 800);
    bool do2 = (k >= 1 && k <= 800);

    // ---- cooperative stage: h1[k-1] + h2[k-2] -> LDS (XOR-swizzled) via wide coherent loads ----
    {
      const char* s1 = (const char*)(A.h1 + ((k - 1) & 1) * 32768);
      const char* s2 = (const char*)(A.h2 + (k & 1) * 32768);
      ulonglong2 d0,d1,d2,d3,d4,d5,d6,d7, e0,e1,e2,e3,e4,e5,e6,e7;
      COH_LOAD8(d0,d1,d2,d3,d4,d5,d6,d7,
                s1 + ((size_t)(0*512)+tid)*16, s1 + ((size_t)(1*512)+tid)*16,
                s1 + ((size_t)(2*512)+tid)*16, s1 + ((size_t)(3*512)+tid)*16,
                s1 + ((size_t)(4*512)+tid)*16, s1 + ((size_t)(5*512)+tid)*16,
                s1 + ((size_t)(6*512)+tid)*16, s1 + ((size_t)(7*512)+tid)*16);
      COH_LOAD8(e0,e1,e2,e3,e4,e5,e6,e7,
                s2 + ((size_t)(0*512)+tid)*16, s2 + ((size_t)(1*512)+tid)*16,
                s2 + ((size_t)(2*512)+tid)*16, s2 + ((size_t)(3*512)+tid)*16,
                s2 + ((size_t)(4*512)+tid)*16, s2 + ((size_t)(5*512)+tid)*16,
                s2 + ((size_t)(6*512)+tid)*16, s2 + ((size_t)(7*512)+tid)*16);
#define STG_WR(j, va, vb)                                            \
      { int m = (j)*512 + tid;                                       \
        int sw = (m * 16) ^ (((m >> 7) & 7) << 4);                   \
        *(ulonglong2*)(smem + sw) = va;                              \
        *(ulonglong2*)(smem + 65536 + sw) = vb; }
      STG_WR(0, d0, e0); STG_WR(1, d1, e1); STG_WR(2, d2, e2); STG_WR(3, d3, e3);
      STG_WR(4, d4, e4); STG_WR(5, d5, e5); STG_WR(6, d6, e6); STG_WR(7, d7, e7);
#undef STG_WR
    }
    __syncthreads();

    if (wid < 2) {
      if (do1) {
        int nn = lane & 15, kq = lane >> 4;
        int brow = wid * 16 + nn;
        int row = (nn >> 2) * 1024 + wg * 4 + (nn & 3);
        f32x4 a0 = {0.f,0.f,0.f,0.f}, a1 = {0.f,0.f,0.f,0.f};
        // x-GEMM (global, cacheable)
        size_t tt = (size_t)(k - k0 + 2);
        const unsigned short* arow = A.inp1c + (tt * 32 + brow) * 1280 + kq * 8;
        const unsigned short* wrow = A.wbf + (size_t)row * 1280 + kq * 8;
#pragma unroll 4
        for (int ks = 0; ks < 40; ks += 2) {
          bfrag8 aA = *(const bfrag8*)(arow + ks * 32);
          bfrag8 aB = *(const bfrag8*)(arow + ks * 32 + 32);
          bfrag8 b0 = *(const bfrag8*)(wrow + ks * 32);
          bfrag8 b1 = *(const bfrag8*)(wrow + ks * 32 + 32);
          a0 = __builtin_amdgcn_mfma_f32_16x16x32_bf16(aA, b0, a0, 0, 0, 0);
          a1 = __builtin_amdgcn_mfma_f32_16x16x32_bf16(aB, b1, a1, 0, 0, 0);
        }
        // h1 from LDS, B-frags from global wimg
        const bfrag8* bp = (const bfrag8*)wimg_wg + lane;
        int sbase = brow * 2048 + kq * 16;
        int sxor = (brow & 7) << 4;
#pragma unroll
        for (int ks = 0; ks < 32; ks += 2) {
          ulonglong2 v0 = *(const ulonglong2*)(smem + ((sbase + ks * 64) ^ sxor));
          ulonglong2 v1 = *(const ulonglong2*)(smem + ((sbase + (ks + 1) * 64) ^ sxor));
          union { unsigned long long q[2]; bfrag8 v; } aa, ab;
          aa.q[0] = v0.x; aa.q[1] = v0.y;
          ab.q[0] = v1.x; ab.q[1] = v1.y;
          a0 = __builtin_amdgcn_mfma_f32_16x16x32_bf16(aa.v, bp[ks * 64], a0, 0, 0, 0);
          a1 = __builtin_amdgcn_mfma_f32_16x16x32_bf16(ab.v, bp[(ks + 1) * 64], a1, 0, 0, 0);
        }
        f32x4 acc = a0 + a1;
#pragma unroll
        for (int q = 0; q < 4; ++q) g1[wid * 16 + kq * 4 + q][nn] = acc[q];
      }
    } else if (wid < 6) {
      if (do2) {
        int mt, imgbase, hoff;
        if (wid < 4) { mt = wid - 2; imgbase = 2048; hoff = 0; }       // h1 staged
        else         { mt = wid - 4; imgbase = 4096; hoff = 65536; }   // h2 staged
        int nn = lane & 15, kq = lane >> 4;
        int brow = mt * 16 + nn;
        f32x4 a0 = {0.f,0.f,0.f,0.f}, a1 = {0.f,0.f,0.f,0.f};
        const bfrag8* bp = (const bfrag8*)wimg_wg + imgbase + lane;
        int sbase = hoff + brow * 2048 + kq * 16;
        int sxor = (brow & 7) << 4;
#pragma unroll
        for (int ks = 0; ks < 32; ks += 2) {
          ulonglong2 v0 = *(const ulonglong2*)(smem + ((sbase + ks * 64) ^ sxor));
          ulonglong2 v1 = *(const ulonglong2*)(smem + ((sbase + (ks + 1) * 64) ^ sxor));
          union { unsigned long long q[2]; bfrag8 v; } aa, ab;
          aa.q[0] = v0.x; aa.q[1] = v0.y;
          ab.q[0] = v1.x; ab.q[1] = v1.y;
          a0 = __builtin_amdgcn_mfma_f32_16x16x32_bf16(aa.v, bp[ks * 64], a0, 0, 0, 0);
          a1 = __builtin_amdgcn_mfma_f32_16x16x32_bf16(ab.v, bp[(ks + 1) * 64], a1, 0, 0, 0);
        }
        f32x4 acc = a0 + a1;
        float (*gb)[17] = (wid < 4) ? g2a : g2b;
#pragma unroll
        for (int q = 0; q < 4; ++q) gb[mt * 16 + kq * 4 + q][nn] = acc[q];
      }
    } else {
      if (k >= 2 && wg < 80) {
        int t = k - 2;
        int L = (wid - 6) * 64 + lane;
        int b = L >> 2, q = L & 3;
        const float* wp = A.Wproj + (size_t)wg * 2048 + q * 256;
        float s0 = 0.f, s1v = 0.f;
        int sbase = 65536 + b * 2048 + q * 512;
        int sxor = (b & 7) << 4;
#pragma unroll 8
        for (int ii = 0; ii < 32; ++ii) {
          ulonglong2 v = *(const ulonglong2*)(smem + ((sbase + ii * 16) ^ sxor));
          union { unsigned long long q; unsigned short u[4]; } a_, b2_;
          a_.q = v.x; b2_.q = v.y;
          const float* w0 = wp + ii * 8;
          s0  += b2f(a_.u[0])*w0[0] + b2f(a_.u[1])*w0[1] + b2f(a_.u[2])*w0[2] + b2f(a_.u[3])*w0[3];
          s1v += b2f(b2_.u[0])*w0[4] + b2f(b2_.u[1])*w0[5] + b2f(b2_.u[2])*w0[6] + b2f(b2_.u[3])*w0[7];
        }
        float s = s0 + s1v;
        s += __shfl_xor(s, 1);
        s += __shfl_xor(s, 2);
        if (q == 0) {
          float add = b2f(A.melpre[((size_t)t * 32 + b) * 80 + wg]);
          A.out_mel[(size_t)b * 64000 + (size_t)wg * 800 + t] = s + add;   // fp32 output
        }
      }
    }
    __syncthreads();
    if (tid < 128) {
      if (do1) {
        int b = tid >> 2, jj = tid & 3;
        float gi = g1[b][jj]      + bias1[jj];
        float gf = g1[b][4 + jj]  + bias1[4 + jj];
        float gg = g1[b][8 + jj]  + bias1[8 + jj];
        float go = g1[b][12 + jj] + bias1[12 + jj];
        float c = c1[b][jj];
        float cn = sigf(gf) * c + sigf(gi) * tanhf(gg);
        c1[b][jj] = cn;
        float hn = sigf(go) * tanhf(cn);
        float ho = __shfl_xor(hn, 1);
        if ((jj & 1) == 0) {
          unsigned int pk = (unsigned int)f2b(hn) | ((unsigned int)f2b(ho) << 16);
          __hip_atomic_store((unsigned int*)(A.h1 + (k & 1) * 32768 + b * 1024 + wg * 4 + jj), pk,
                             __ATOMIC_RELAXED, AGENT);
        }
      }
    } else if (tid < 256) {
      if (do2) {
        int b = (tid - 128) >> 2, jj = tid & 3;
        float gi = g2a[b][jj]      + g2b[b][jj]      + bias2[jj];
        float gf = g2a[b][4 + jj]  + g2b[b][4 + jj]  + bias2[4 + jj];
        float gg = g2a[b][8 + jj]  + g2b[b][8 + jj]  + bias2[8 + jj];
        float go = g2a[b][12 + jj] + g2b[b][12 + jj] + bias2[12 + jj];
        float c = c2[b][jj];
        float cn = sigf(gf) * c + sigf(gi) * tanhf(gg);
        c2[b][jj] = cn;
        float hn = sigf(go) * tanhf(cn);
        float ho = __shfl_xor(hn, 1);
        if ((jj & 1) == 0) {
          unsigned int pk = (unsigned int)f2b(hn) | ((unsigned int)f2b(ho) << 16);
          __hip_atomic_store((unsigned int*)(A.h2 + ((k - 1) & 1) * 32768 + b * 1024 + wg * 4 + jj), pk,
                             __ATOMIC_RELAXED, AGENT);
        }
      }
    }
    __syncthreads();   // drains vmcnt(0): all h-stores of this WG committed before arrive
    if (tid == 0) {
      asm volatile("s_waitcnt vmcnt(0)" ::: "memory");
      __hip_atomic_fetch_add(A.cnt + (wg & 15) * 16, 1u, __ATOMIC_RELAXED, AGENT);
    }
    if (tid < 16 && totspin >= 0) {
      unsigned int tgt = (unsigned int)(k + 1) * 16u;
      while (__hip_atomic_load(A.cnt + tid * 16, __ATOMIC_RELAXED, AGENT) < tgt) {
        __builtin_amdgcn_s_sleep(8);
        if (++totspin > (1l << 25)) {          // watchdog: record + free-run, never hang
          totspin = -1;
          __hip_atomic_fetch_add(A.cnt + 255, 1u, __ATOMIC_RELAXED, AGENT);
          break;
        }
      }
    }
    __syncthreads();
  }
  if (tid < 128) {
    int b = tid >> 2, jj = tid & 3;
    A.cst[((size_t)wg * 32 + b) * 4 + jj] = c1[b][jj];
  } else if (tid < 256) {
    int b = (tid - 128) >> 2, jj = tid & 3;
    A.cst[32768 + ((size_t)wg * 32 + b) * 4 + jj] = c2[b][jj];
  }
}

// ---------------- diagnostics (fp32) ----------------
__global__ void k_diag(float* out_mel, float wsmb) {
  out_mel[0] = 1000.f + wsmb;                 // ~1000+MB => ws too small
}
__global__ void k_verify(const unsigned int* cnt, float* out_mel) {
  unsigned int tot = 0;
  for (int i = 0; i < 16; ++i) tot += cnt[i * 16];
  unsigned int wd = cnt[255];
  if (wd)
    out_mel[0] = 5000.f + (float)(wd > 900u ? 900u : wd);      // ~5000+ => barrier desync
  else if (tot != 802u * 256u)
    out_mel[0] = 3000.f + (float)tot * (1.f / 256.f);          // ~3000+ => decode stalled
}

extern "C" void kernel_launch(void* const* d_in, const int* in_sizes, int n_in,
                              void* d_out, int out_size, void* d_ws, size_t ws_size,
                              hipStream_t stream) {
  const float* memory = (const float*)d_in[0];
  const float* dur    = (const float*)d_in[1];
  const int*   dfi    = (const int*)d_in[2];
  const float* range  = (const float*)d_in[3];
  const float* din    = (const float*)d_in[4];
  const float* Wp1    = (const float*)d_in[6];
  const float* Wp2    = (const float*)d_in[7];
  const float* Wih1   = (const float*)d_in[8];
  const float* Whh1   = (const float*)d_in[9];
  const float* bih1   = (const float*)d_in[10];
  const float* bhh1   = (const float*)d_in[11];
  const float* Wih2   = (const float*)d_in[12];
  const float* Whh2   = (const float*)d_in[13];
  const float* bih2   = (const float*)d_in[14];
  const float* bhh2   = (const float*)d_in[15];
  const float* Wproj  = (const float*)d_in[16];
  const float* bproj  = (const float*)d_in[17];
  const float* u1     = (const float*)d_in[18];
  const float* u2     = (const float*)d_in[19];

  char* ws = (char*)d_ws;
  unsigned int* cnt   = (unsigned int*)ws;
  float* cvec         = (float*)(ws + 4096);
  float* coef         = cvec + 8192;
  float* inv2         = coef + 8192;
  float* pe           = (float*)(ws + 102400);
  unsigned short* h1  = (unsigned short*)(ws + 153600);
  unsigned short* h2  = h1 + 65536;
  float* cst          = (float*)(ws + 415744);
  unsigned short* melpre = (unsigned short*)(ws + 720896);
  unsigned short* wbf    = (unsigned short*)(ws + 4849664);
  unsigned short* wimg   = (unsigned short*)(ws + 15728640);
  unsigned short* inp1c  = (unsigned short*)(ws + 41943040ull);

  float* out_mel   = (float*)d_out;                         // fp32 outputs (reference dtype)
  float* out_align = out_mel + 2048000;

  const size_t BASE = 41943040ull;
  int TC;
  if      (ws_size >= BASE + 802ull * 81920ull) TC = 800;
  else if (ws_size >= BASE + 202ull * 81920ull) TC = 200;
  else if (ws_size >= BASE +  82ull * 81920ull) TC = 80;
  else if (ws_size >= BASE +  42ull * 81920ull) TC = 40;
  else {
    k_diag<<<1, 1, 0, stream>>>(out_mel, (float)(ws_size >> 20));
    return;
  }

  hipFuncSetAttribute((const void*)k_decode, hipFuncAttributeMaxDynamicSharedMemorySize, 147456);
  hipFuncSetAttribute((const void*)k_melpre, hipFuncAttributeMaxDynamicSharedMemorySize, 98304);

  k_init<<<256, 256, 0, stream>>>((unsigned int*)(ws + 153600), cnt, pe);
  k_attn_prep<<<32, 256, 0, stream>>>(dur, range, cvec, coef, inv2);
  k_attn<<<dim3(800, 32), 256, 0, stream>>>(cvec, coef, inv2, out_align);
  k_repackW<<<5120, 256, 0, stream>>>(Wih1, wbf);
  k_repackImg<<<49152, 256, 0, stream>>>(Whh1, Wih2, Whh2, wimg);

  DecArgs da[20];
  int nch = (800 + TC - 1) / TC;
  for (int c = 0; c < nch; ++c) {
    int k0 = c * TC;
    int k1 = (c == nch - 1) ? 802 : (c + 1) * TC;
    int t0 = k0 - 2;
    int tbeg = t0 < 0 ? 0 : t0;
    int tend = k1 < 800 ? k1 : 800;
    int R = tend - tbeg;
    k_prenet<<<R, 256, 0, stream>>>(din, u1, u2, Wp1, Wp2, inp1c, t0, tbeg);
    k_ctx<<<dim3((R + 15) / 16, 32), 256, 0, stream>>>(cvec, coef, inv2, memory, inp1c, t0, tbeg, tend);
    k_pegather<<<(R * 4096 + 255) / 256, 256, 0, stream>>>(dfi, pe, inp1c, t0, tbeg, R);
    k_melpre<<<R, 256, 65536, stream>>>(inp1c, Wproj, bproj, melpre, t0, tbeg);

    da[c] = DecArgs{ inp1c, wbf, wimg, bih1, bhh1, bih2, bhh2,
                     Wproj, bproj, melpre, h1, h2, cst, cnt, out_mel, k0, k1 };
    void* kp[1] = { &da[c] };
    hipLaunchCooperativeKernel((const void*)k_decode, dim3(256), dim3(512), kp, 139264, stream);
  }
  k_verify<<<1, 1, 0, stream>>>(cnt, out_mel);
}